// Round 14
// baseline (167.309 us; speedup 1.0000x reference)
//
#include <hip/hip_runtime.h>

// MHA forward: B=4, S=2048, D=768, H=12, Hd=64
// prep -> qkv GEMM (BK=64 swizzled LDS, XCD-swizzled grid) -> flash attn
// (swapped-QK, in-reg softmax, 16 q-rows/wave, 64-row blocks, 5 blocks/CU)
// -> proj GEMM.

typedef _Float16 f16;
typedef _Float16 f16x8 __attribute__((ext_vector_type(8)));
typedef _Float16 f16x4 __attribute__((ext_vector_type(4)));
typedef float f32x4 __attribute__((ext_vector_type(4)));

#define BQ 4
#define SQ 2048
#define DQ 768
#define HQ 12
#define HD 64
#define M_TOK (BQ*SQ)      // 8192
#define KVB 64
#define QSCALE 0.18033688f  // 0.125 * log2(e): scores land in exp2 domain
#define THR_LOG2 11.5f      // defer-max threshold (~e^8)

__device__ __forceinline__ void gld_lds16(const f16* g, f16* l) {
  __builtin_amdgcn_global_load_lds((const __attribute__((address_space(1))) void*)g,
                                   (__attribute__((address_space(3))) void*)l,
                                   16, 0, 0);
}

// ---- prep: cvt x (blocks 0..6143), transpose w_qkv (6144..7871), w_proj (7872..8447)
__global__ __launch_bounds__(256)
void prep(const float* __restrict__ x, f16* __restrict__ xh,
          const float* __restrict__ w_qkv, f16* __restrict__ wqkvT,
          const float* __restrict__ w_proj, f16* __restrict__ wprojT)
{
  __shared__ float tile[32][33];
  const int bid = blockIdx.x, tid = threadIdx.x;
  if (bid < 6144) {
    int i = (bid * 256 + tid) * 4;
    float4 v = *(const float4*)(x + i);
    f16x4 o = { (f16)v.x, (f16)v.y, (f16)v.z, (f16)v.w };
    *(f16x4*)(xh + i) = o;
    return;
  }
  const float* w; f16* wt; int K, N, nb, kb;
  if (bid < 7872) {
    int b2 = bid - 6144; w = w_qkv; wt = wqkvT; K = DQ; N = 3 * DQ;
    nb = (b2 % 72) * 32; kb = (b2 / 72) * 32;
  } else {
    int b3 = bid - 7872; w = w_proj; wt = wprojT; K = DQ; N = DQ;
    nb = (b3 % 24) * 32; kb = (b3 / 24) * 32;
  }
  int tx = tid & 31, ty = tid >> 5;
  for (int r = ty; r < 32; r += 8)
    tile[r][tx] = w[(size_t)(kb + r) * N + nb + tx];
  __syncthreads();
  for (int r = ty; r < 32; r += 8)
    wt[(size_t)(nb + r) * K + kb + tx] = (f16)tile[tx][r];
}

// ---- 128x128 tile GEMM, A [M][K] f16, Bt [N][K] f16, BK=64, dbuf, swizzled ----
template<int MODE>
__global__ __launch_bounds__(256, 2)
void gemm128(const f16* __restrict__ A, const f16* __restrict__ Bt,
             const float* __restrict__ bias, float* __restrict__ Cf,
             f16* __restrict__ Qb, f16* __restrict__ Kb, f16* __restrict__ Vt,
             int M, int N, int K, int nbx)
{
  __shared__ f16 Ash[2][128 * 64];   // 2 x 16 KB
  __shared__ f16 Bsh[2][128 * 64];   // 2 x 16 KB
  const int tid = threadIdx.x;
  const int cpx = gridDim.x >> 3;
  const int bid = (blockIdx.x & 7) * cpx + (blockIdx.x >> 3);
  const int nb = bid % nbx, mb = bid / nbx;
  const int m0 = mb * 128, n0 = nb * 128;
  const int lane = tid & 63, wid = tid >> 6;
  const int wr = wid >> 1, wc = wid & 1;
  const int l16 = lane & 15, l4 = lane >> 4;

  f32x4 acc[4][4] = {};

  const f16* aP[4]; const f16* bP[4]; int lOff[4];
  #pragma unroll
  for (int j = 0; j < 4; ++j) {
    int q = j * 256 + tid;
    int r = q >> 3;
    int sc = ((q & 7) ^ (r & 7)) * 8;     // pre-XOR'd source col
    aP[j] = A  + (size_t)(m0 + r) * K + sc;
    bP[j] = Bt + (size_t)(n0 + r) * K + sc;
    lOff[j] = q * 8;
  }

#define GSTAGE(buf, k0)                                   \
  do {                                                    \
    _Pragma("unroll")                                     \
    for (int j = 0; j < 4; ++j) {                         \
      gld_lds16(aP[j] + (k0), Ash[buf] + lOff[j]);        \
      gld_lds16(bP[j] + (k0), Bsh[buf] + lOff[j]);        \
    }                                                     \
  } while (0)

  GSTAGE(0, 0);
  __syncthreads();
  for (int k0 = 0; k0 < K; k0 += 64) {
    const int buf = (k0 >> 6) & 1;
    if (k0 + 64 < K) GSTAGE(buf ^ 1, k0 + 64);
    #pragma unroll
    for (int kk = 0; kk < 2; ++kk) {
      f16x8 af[4], bfr[4];
      #pragma unroll
      for (int m = 0; m < 4; ++m) {
        int R = wr * 64 + m * 16 + l16;
        af[m] = *(const f16x8*)(Ash[buf] + R * 64 + (((kk * 4 + l4) ^ (R & 7)) * 8));
      }
      #pragma unroll
      for (int n = 0; n < 4; ++n) {
        int R = wc * 64 + n * 16 + l16;
        bfr[n] = *(const f16x8*)(Bsh[buf] + R * 64 + (((kk * 4 + l4) ^ (R & 7)) * 8));
      }
      #pragma unroll
      for (int m = 0; m < 4; ++m)
        #pragma unroll
        for (int n = 0; n < 4; ++n)
          acc[m][n] = __builtin_amdgcn_mfma_f32_16x16x32_f16(af[m], bfr[n], acc[m][n], 0, 0, 0);
    }
    __syncthreads();
  }
#undef GSTAGE

  const int cbase = n0 + wc * 64;
  const int rbase = m0 + wr * 64;
  if (MODE == 1) {
    #pragma unroll
    for (int n = 0; n < 4; ++n) {
      int c = cbase + n * 16 + l16;
      float bv = bias[c];
      #pragma unroll
      for (int m = 0; m < 4; ++m)
        #pragma unroll
        for (int r = 0; r < 4; ++r) {
          int rr = rbase + m * 16 + l4 * 4 + r;
          Cf[(size_t)rr * N + c] = acc[m][n][r] + bv;
        }
    }
  } else {
    #pragma unroll
    for (int n = 0; n < 4; ++n) {
      int c = cbase + n * 16 + l16;
      float bv = bias[c];
      int which = c / DQ;
      int rem = c - which * DQ;
      int h = rem >> 6, hd = rem & 63;
      #pragma unroll
      for (int m = 0; m < 4; ++m) {
        int rr0 = rbase + m * 16 + l4 * 4;
        int b = rr0 >> 11, s = rr0 & 2047;
        size_t bh = (size_t)(b * HQ + h);
        if (which == 2) {
          f16x4 ov = { (f16)(acc[m][n][0] + bv), (f16)(acc[m][n][1] + bv),
                       (f16)(acc[m][n][2] + bv), (f16)(acc[m][n][3] + bv) };
          *(f16x4*)(Vt + (bh * HD + hd) * SQ + s) = ov;
        } else if (which == 0) {
          #pragma unroll
          for (int r = 0; r < 4; ++r)
            Qb[(bh * SQ + s + r) * HD + hd] = (f16)((acc[m][n][r] + bv) * QSCALE);
        } else {
          #pragma unroll
          for (int r = 0; r < 4; ++r)
            Kb[(bh * SQ + s + r) * HD + hd] = (f16)(acc[m][n][r] + bv);
        }
      }
    }
  }
}

// K-row permutation (C-slot -> PV B-slot mapping)
__device__ __forceinline__ int permK(int p) {
  return ((p & 16) << 1) | (((p >> 2) & 3) << 3) | ((p & 32) >> 3) | (p & 3);
}

// ---- flash attention: 64 q-rows/block (4 waves x 16 rows), KVB=64 dbuf,
// grid 1536 -> 5 blocks/CU (LDS-capped) = 5 waves/SIMD for latency hiding.
// Same per-row math/order as R13 -> absmax bit-identical.
__global__ __launch_bounds__(256, 5)
void attn(const f16* __restrict__ Qb, const f16* __restrict__ Kb,
          const f16* __restrict__ Vt, f16* __restrict__ O)
{
  __shared__ f16 Ksh[2][KVB * HD];
  __shared__ f16 Vsh[2][HD * KVB];
  const int tid = threadIdx.x, lane = tid & 63, wid = tid >> 6;
  const int l16 = lane & 15, l4 = lane >> 4;

  const int nwg = gridDim.x;
  const int cpx = nwg >> 3;
  const int swz = (blockIdx.x & 7) * cpx + (blockIdx.x >> 3);
  const int qt = swz & 31, bh = swz >> 5;   // 32 q-tiles of 64 rows
  const int b = bh / HQ, h = bh - b * HQ;
  const f16* q  = Qb + (size_t)bh * SQ * HD;
  const f16* kp = Kb + (size_t)bh * SQ * HD;
  const f16* vp = Vt + (size_t)bh * HD * SQ;
  const int s0 = qt * 64 + wid * 16;

  f16x8 qf[2];
  #pragma unroll
  for (int kk = 0; kk < 2; ++kk)
    qf[kk] = *(const f16x8*)(q + (size_t)(s0 + l16) * HD + kk * 32 + l4 * 8);

  f32x4 oacc[4] = {};
  float mrun = -1e30f, lrun = 0.f;

  const int p0 = tid >> 3, p1 = (tid >> 3) + 32;
  const int scS = ((tid & 7) ^ (p0 & 7)) * 8;
  const int kr0 = permK(p0), kr1 = permK(p1);

#define STAGE(buf, t0)                                                        \
  do {                                                                        \
    gld_lds16(kp + (size_t)((t0) + kr0) * HD + scS, Ksh[buf] + tid * 8);      \
    gld_lds16(kp + (size_t)((t0) + kr1) * HD + scS, Ksh[buf] + (tid + 256) * 8);\
    gld_lds16(vp + (size_t)p0 * SQ + (t0) + scS,   Vsh[buf] + tid * 8);       \
    gld_lds16(vp + (size_t)p1 * SQ + (t0) + scS,   Vsh[buf] + (tid + 256) * 8);\
  } while (0)

#define COMPUTE(buf)                                                          \
  do {                                                                        \
    f32x4 sacc[4] = {};                                                       \
    __builtin_amdgcn_s_setprio(1);                                            \
    _Pragma("unroll")                                                         \
    for (int kk = 0; kk < 2; ++kk) {                                          \
      f16x8 kf[4];                                                            \
      _Pragma("unroll")                                                       \
      for (int n = 0; n < 4; ++n)                                             \
        kf[n] = *(const f16x8*)(Ksh[buf] + (n * 16 + l16) * HD +              \
                                ((kk * 32 + l4 * 8) ^ ((l16 & 7) * 8)));      \
      _Pragma("unroll")                                                       \
      for (int n = 0; n < 4; ++n)                                             \
        sacc[n] = __builtin_amdgcn_mfma_f32_16x16x32_f16(kf[n], qf[kk], sacc[n], 0, 0, 0); \
    }                                                                         \
    __builtin_amdgcn_s_setprio(0);                                            \
    float rm = -1e30f;                                                        \
    _Pragma("unroll")                                                         \
    for (int n = 0; n < 4; ++n)                                               \
      rm = fmaxf(rm, fmaxf(fmaxf(sacc[n][0], sacc[n][1]),                     \
                           fmaxf(sacc[n][2], sacc[n][3])));                   \
    rm = fmaxf(rm, __shfl_xor(rm, 16));                                       \
    rm = fmaxf(rm, __shfl_xor(rm, 32));                                       \
    if (!__all(rm - mrun <= THR_LOG2)) {                                      \
      float mn = fmaxf(mrun, rm);                                             \
      float corr = __builtin_amdgcn_exp2f(mrun - mn);                         \
      lrun *= corr;                                                           \
      _Pragma("unroll")                                                       \
      for (int n = 0; n < 4; ++n)                                             \
        oacc[n] *= corr;                                                      \
      mrun = mn;                                                              \
    }                                                                         \
    float mref = mrun;                                                        \
    float ps = 0.f;                                                           \
    f16x8 bfr[2];                                                             \
    _Pragma("unroll")                                                         \
    for (int n = 0; n < 4; ++n)                                               \
      _Pragma("unroll")                                                       \
      for (int r = 0; r < 4; ++r) {                                           \
        float pv = __builtin_amdgcn_exp2f(sacc[n][r] - mref);                 \
        bfr[n & 1][(n >> 1) * 4 + r] = (f16)pv;                               \
        ps += pv;                                                             \
      }                                                                       \
    ps += __shfl_xor(ps, 16);                                                 \
    ps += __shfl_xor(ps, 32);                                                 \
    lrun += ps;                                                               \
    __builtin_amdgcn_s_setprio(1);                                            \
    _Pragma("unroll")                                                         \
    for (int kk = 0; kk < 2; ++kk) {                                          \
      f16x8 vf[4];                                                            \
      _Pragma("unroll")                                                       \
      for (int n = 0; n < 4; ++n)                                             \
        vf[n] = *(const f16x8*)(Vsh[buf] + (n * 16 + l16) * KVB +             \
                                ((kk * 32 + l4 * 8) ^ ((l16 & 7) * 8)));      \
      _Pragma("unroll")                                                       \
      for (int n = 0; n < 4; ++n)                                             \
        oacc[n] = __builtin_amdgcn_mfma_f32_16x16x32_f16(vf[n], bfr[kk], oacc[n], 0, 0, 0); \
    }                                                                         \
    __builtin_amdgcn_s_setprio(0);                                            \
  } while (0)

  STAGE(0, 0);
  __syncthreads();
  for (int t0 = 0; t0 < SQ; t0 += 2 * KVB) {
    STAGE(1, t0 + KVB);
    COMPUTE(0);
    __syncthreads();
    if (t0 + 2 * KVB < SQ) STAGE(0, t0 + 2 * KVB);
    COMPUTE(1);
    __syncthreads();
  }
#undef STAGE
#undef COMPUTE

  {
    float inv = 1.f / lrun;
    const int s = s0 + l16;
    f16* obase = O + ((size_t)b * SQ + s) * DQ + h * HD + l4 * 4;
    #pragma unroll
    for (int n = 0; n < 4; ++n) {
      f16x4 ov = { (f16)(oacc[n][0] * inv), (f16)(oacc[n][1] * inv),
                   (f16)(oacc[n][2] * inv), (f16)(oacc[n][3] * inv) };
      *(f16x4*)(obase + n * 16) = ov;
    }
  }
}

extern "C" void kernel_launch(void* const* d_in, const int* in_sizes, int n_in,
                              void* d_out, int out_size, void* d_ws, size_t ws_size,
                              hipStream_t stream) {
  const float* x      = (const float*)d_in[0];
  const float* w_qkv  = (const float*)d_in[1];
  const float* b_qkv  = (const float*)d_in[2];
  const float* w_proj = (const float*)d_in[3];
  const float* b_proj = (const float*)d_in[4];
  float* out = (float*)d_out;

  char* ws = (char*)d_ws;
  f16* xh     = (f16*)ws; ws += (size_t)M_TOK * DQ * 2;
  f16* wqkvT  = (f16*)ws; ws += (size_t)3 * DQ * DQ * 2;
  f16* wprojT = (f16*)ws; ws += (size_t)DQ * DQ * 2;
  f16* Qb     = (f16*)ws; ws += (size_t)M_TOK * DQ * 2;
  f16* Kb     = (f16*)ws; ws += (size_t)M_TOK * DQ * 2;
  f16* Vt     = (f16*)ws; ws += (size_t)M_TOK * DQ * 2;
  f16* AO     = xh;  // attn output; xh fully consumed by qkv GEMM before attn

  prep<<<8448, 256, 0, stream>>>(x, xh, w_qkv, wqkvT, w_proj, wprojT);

  gemm128<0><<<(M_TOK / 128) * (3 * DQ / 128), 256, 0, stream>>>(
      xh, wqkvT, b_qkv, nullptr, Qb, Kb, Vt, M_TOK, 3 * DQ, DQ, 3 * DQ / 128);

  attn<<<BQ * HQ * (SQ / 64), 256, 0, stream>>>(Qb, Kb, Vt, AO);

  gemm128<1><<<(M_TOK / 128) * (DQ / 128), 256, 0, stream>>>(
      AO, wprojT, b_proj, out, nullptr, nullptr, nullptr, M_TOK, DQ, DQ, DQ / 128);
}

// Round 15
// 149.987 us; speedup vs baseline: 1.1155x; 1.1155x over previous
//
#include <hip/hip_runtime.h>

// MHA forward: B=4, S=2048, D=768, H=12, Hd=64
// prep -> qkv GEMM (BK=64 swizzled LDS, XCD-swizzled grid) -> flash attn
// (R13 base + branch-local max-shfl + deferred per-lane l-sum) -> proj GEMM.

typedef _Float16 f16;
typedef _Float16 f16x8 __attribute__((ext_vector_type(8)));
typedef _Float16 f16x4 __attribute__((ext_vector_type(4)));
typedef float f32x4 __attribute__((ext_vector_type(4)));

#define BQ 4
#define SQ 2048
#define DQ 768
#define HQ 12
#define HD 64
#define M_TOK (BQ*SQ)      // 8192
#define KVB 64
#define QSCALE 0.18033688f  // 0.125 * log2(e): scores land in exp2 domain
#define THR_LOG2 11.5f      // defer-max threshold (~e^8)

__device__ __forceinline__ void gld_lds16(const f16* g, f16* l) {
  __builtin_amdgcn_global_load_lds((const __attribute__((address_space(1))) void*)g,
                                   (__attribute__((address_space(3))) void*)l,
                                   16, 0, 0);
}

// ---- prep: cvt x (blocks 0..6143), transpose w_qkv (6144..7871), w_proj (7872..8447)
__global__ __launch_bounds__(256)
void prep(const float* __restrict__ x, f16* __restrict__ xh,
          const float* __restrict__ w_qkv, f16* __restrict__ wqkvT,
          const float* __restrict__ w_proj, f16* __restrict__ wprojT)
{
  __shared__ float tile[32][33];
  const int bid = blockIdx.x, tid = threadIdx.x;
  if (bid < 6144) {
    int i = (bid * 256 + tid) * 4;
    float4 v = *(const float4*)(x + i);
    f16x4 o = { (f16)v.x, (f16)v.y, (f16)v.z, (f16)v.w };
    *(f16x4*)(xh + i) = o;
    return;
  }
  const float* w; f16* wt; int K, N, nb, kb;
  if (bid < 7872) {
    int b2 = bid - 6144; w = w_qkv; wt = wqkvT; K = DQ; N = 3 * DQ;
    nb = (b2 % 72) * 32; kb = (b2 / 72) * 32;
  } else {
    int b3 = bid - 7872; w = w_proj; wt = wprojT; K = DQ; N = DQ;
    nb = (b3 % 24) * 32; kb = (b3 / 24) * 32;
  }
  int tx = tid & 31, ty = tid >> 5;
  for (int r = ty; r < 32; r += 8)
    tile[r][tx] = w[(size_t)(kb + r) * N + nb + tx];
  __syncthreads();
  for (int r = ty; r < 32; r += 8)
    wt[(size_t)(nb + r) * K + kb + tx] = (f16)tile[tx][r];
}

// ---- 128x128 tile GEMM, A [M][K] f16, Bt [N][K] f16, BK=64, dbuf, swizzled ----
template<int MODE>
__global__ __launch_bounds__(256, 2)
void gemm128(const f16* __restrict__ A, const f16* __restrict__ Bt,
             const float* __restrict__ bias, float* __restrict__ Cf,
             f16* __restrict__ Qb, f16* __restrict__ Kb, f16* __restrict__ Vt,
             int M, int N, int K, int nbx)
{
  __shared__ f16 Ash[2][128 * 64];   // 2 x 16 KB
  __shared__ f16 Bsh[2][128 * 64];   // 2 x 16 KB
  const int tid = threadIdx.x;
  const int cpx = gridDim.x >> 3;
  const int bid = (blockIdx.x & 7) * cpx + (blockIdx.x >> 3);
  const int nb = bid % nbx, mb = bid / nbx;
  const int m0 = mb * 128, n0 = nb * 128;
  const int lane = tid & 63, wid = tid >> 6;
  const int wr = wid >> 1, wc = wid & 1;
  const int l16 = lane & 15, l4 = lane >> 4;

  f32x4 acc[4][4] = {};

  const f16* aP[4]; const f16* bP[4]; int lOff[4];
  #pragma unroll
  for (int j = 0; j < 4; ++j) {
    int q = j * 256 + tid;
    int r = q >> 3;
    int sc = ((q & 7) ^ (r & 7)) * 8;     // pre-XOR'd source col
    aP[j] = A  + (size_t)(m0 + r) * K + sc;
    bP[j] = Bt + (size_t)(n0 + r) * K + sc;
    lOff[j] = q * 8;
  }

#define GSTAGE(buf, k0)                                   \
  do {                                                    \
    _Pragma("unroll")                                     \
    for (int j = 0; j < 4; ++j) {                         \
      gld_lds16(aP[j] + (k0), Ash[buf] + lOff[j]);        \
      gld_lds16(bP[j] + (k0), Bsh[buf] + lOff[j]);        \
    }                                                     \
  } while (0)

  GSTAGE(0, 0);
  __syncthreads();
  for (int k0 = 0; k0 < K; k0 += 64) {
    const int buf = (k0 >> 6) & 1;
    if (k0 + 64 < K) GSTAGE(buf ^ 1, k0 + 64);
    #pragma unroll
    for (int kk = 0; kk < 2; ++kk) {
      f16x8 af[4], bfr[4];
      #pragma unroll
      for (int m = 0; m < 4; ++m) {
        int R = wr * 64 + m * 16 + l16;
        af[m] = *(const f16x8*)(Ash[buf] + R * 64 + (((kk * 4 + l4) ^ (R & 7)) * 8));
      }
      #pragma unroll
      for (int n = 0; n < 4; ++n) {
        int R = wc * 64 + n * 16 + l16;
        bfr[n] = *(const f16x8*)(Bsh[buf] + R * 64 + (((kk * 4 + l4) ^ (R & 7)) * 8));
      }
      #pragma unroll
      for (int m = 0; m < 4; ++m)
        #pragma unroll
        for (int n = 0; n < 4; ++n)
          acc[m][n] = __builtin_amdgcn_mfma_f32_16x16x32_f16(af[m], bfr[n], acc[m][n], 0, 0, 0);
    }
    __syncthreads();
  }
#undef GSTAGE

  const int cbase = n0 + wc * 64;
  const int rbase = m0 + wr * 64;
  if (MODE == 1) {
    #pragma unroll
    for (int n = 0; n < 4; ++n) {
      int c = cbase + n * 16 + l16;
      float bv = bias[c];
      #pragma unroll
      for (int m = 0; m < 4; ++m)
        #pragma unroll
        for (int r = 0; r < 4; ++r) {
          int rr = rbase + m * 16 + l4 * 4 + r;
          Cf[(size_t)rr * N + c] = acc[m][n][r] + bv;
        }
    }
  } else {
    #pragma unroll
    for (int n = 0; n < 4; ++n) {
      int c = cbase + n * 16 + l16;
      float bv = bias[c];
      int which = c / DQ;
      int rem = c - which * DQ;
      int h = rem >> 6, hd = rem & 63;
      #pragma unroll
      for (int m = 0; m < 4; ++m) {
        int rr0 = rbase + m * 16 + l4 * 4;
        int b = rr0 >> 11, s = rr0 & 2047;
        size_t bh = (size_t)(b * HQ + h);
        if (which == 2) {
          f16x4 ov = { (f16)(acc[m][n][0] + bv), (f16)(acc[m][n][1] + bv),
                       (f16)(acc[m][n][2] + bv), (f16)(acc[m][n][3] + bv) };
          *(f16x4*)(Vt + (bh * HD + hd) * SQ + s) = ov;
        } else if (which == 0) {
          #pragma unroll
          for (int r = 0; r < 4; ++r)
            Qb[(bh * SQ + s + r) * HD + hd] = (f16)((acc[m][n][r] + bv) * QSCALE);
        } else {
          #pragma unroll
          for (int r = 0; r < 4; ++r)
            Kb[(bh * SQ + s + r) * HD + hd] = (f16)(acc[m][n][r] + bv);
        }
      }
    }
  }
}

// K-row permutation (C-slot -> PV B-slot mapping)
__device__ __forceinline__ int permK(int p) {
  return ((p & 16) << 1) | (((p >> 2) & 3) << 3) | ((p & 32) >> 3) | (p & 3);
}

// ---- flash attention: R13 structure (128 rows/block, 2 groups/wave) with
// (a) max-shfls moved inside the rescale branch (defer-check on per-lane
// partial max — logically identical condition), (b) per-lane l accumulation,
// row-reduced once in the epilogue.
__global__ __launch_bounds__(256, 3)
void attn(const f16* __restrict__ Qb, const f16* __restrict__ Kb,
          const f16* __restrict__ Vt, f16* __restrict__ O)
{
  __shared__ f16 Ksh[2][KVB * HD];
  __shared__ f16 Vsh[2][HD * KVB];
  const int tid = threadIdx.x, lane = tid & 63, wid = tid >> 6;
  const int l16 = lane & 15, l4 = lane >> 4;

  const int nwg = gridDim.x;
  const int cpx = nwg >> 3;
  const int swz = (blockIdx.x & 7) * cpx + (blockIdx.x >> 3);
  const int qt = swz & 15, bh = swz >> 4;
  const int b = bh / HQ, h = bh - b * HQ;
  const f16* q  = Qb + (size_t)bh * SQ * HD;
  const f16* kp = Kb + (size_t)bh * SQ * HD;
  const f16* vp = Vt + (size_t)bh * HD * SQ;
  const int s0 = qt * 128 + wid * 32;

  f16x8 qf[2][2];
  #pragma unroll
  for (int g = 0; g < 2; ++g)
    #pragma unroll
    for (int kk = 0; kk < 2; ++kk)
      qf[g][kk] = *(const f16x8*)(q + (size_t)(s0 + g * 16 + l16) * HD + kk * 32 + l4 * 8);

  f32x4 oacc[2][4] = {};
  float mrun[2] = { -1e30f, -1e30f };
  float lrun[2] = { 0.f, 0.f };        // per-lane partial sums (row-reduced at end)

  const int p0 = tid >> 3, p1 = (tid >> 3) + 32;
  const int scS = ((tid & 7) ^ (p0 & 7)) * 8;
  const int kr0 = permK(p0), kr1 = permK(p1);

#define STAGE(buf, t0)                                                        \
  do {                                                                        \
    gld_lds16(kp + (size_t)((t0) + kr0) * HD + scS, Ksh[buf] + tid * 8);      \
    gld_lds16(kp + (size_t)((t0) + kr1) * HD + scS, Ksh[buf] + (tid + 256) * 8);\
    gld_lds16(vp + (size_t)p0 * SQ + (t0) + scS,   Vsh[buf] + tid * 8);       \
    gld_lds16(vp + (size_t)p1 * SQ + (t0) + scS,   Vsh[buf] + (tid + 256) * 8);\
  } while (0)

// softmax for group g: per-lane partial max for the defer-check; cross-lane
// max only inside the (rare) rescale branch; l accumulated per-lane.
#define SOFTMAX(g)                                                            \
  do {                                                                        \
    float rm = -1e30f;                                                        \
    _Pragma("unroll")                                                         \
    for (int n = 0; n < 4; ++n)                                               \
      rm = fmaxf(rm, fmaxf(fmaxf(sacc[g][n][0], sacc[g][n][1]),               \
                           fmaxf(sacc[g][n][2], sacc[g][n][3])));             \
    if (!__all(rm - mrun[g] <= THR_LOG2)) {                                   \
      rm = fmaxf(rm, __shfl_xor(rm, 16));                                     \
      rm = fmaxf(rm, __shfl_xor(rm, 32));                                     \
      float mn = fmaxf(mrun[g], rm);                                          \
      float corr = __builtin_amdgcn_exp2f(mrun[g] - mn);                      \
      lrun[g] *= corr;                                                        \
      _Pragma("unroll")                                                       \
      for (int n = 0; n < 4; ++n)                                             \
        oacc[g][n] *= corr;                                                   \
      mrun[g] = mn;                                                           \
    }                                                                         \
    float mref = mrun[g];                                                     \
    float ps = 0.f;                                                           \
    _Pragma("unroll")                                                         \
    for (int n = 0; n < 4; ++n)                                               \
      _Pragma("unroll")                                                       \
      for (int r = 0; r < 4; ++r) {                                           \
        float pv = __builtin_amdgcn_exp2f(sacc[g][n][r] - mref);              \
        bfr[g][n & 1][(n >> 1) * 4 + r] = (f16)pv;                            \
        ps += pv;                                                             \
      }                                                                       \
    lrun[g] += ps;                                                            \
  } while (0)

#define COMPUTE(buf)                                                          \
  do {                                                                        \
    f32x4 sacc[2][4] = {};                                                    \
    f16x8 kf[2][4];                                                           \
    _Pragma("unroll")                                                         \
    for (int kk = 0; kk < 2; ++kk)                                            \
      _Pragma("unroll")                                                       \
      for (int n = 0; n < 4; ++n)                                             \
        kf[kk][n] = *(const f16x8*)(Ksh[buf] + (n * 16 + l16) * HD +          \
                                    ((kk * 32 + l4 * 8) ^ ((l16 & 7) * 8)));  \
    __builtin_amdgcn_s_setprio(1);                                            \
    _Pragma("unroll")                                                         \
    for (int kk = 0; kk < 2; ++kk)                                            \
      _Pragma("unroll")                                                       \
      for (int n = 0; n < 4; ++n)                                             \
        sacc[0][n] = __builtin_amdgcn_mfma_f32_16x16x32_f16(kf[kk][n], qf[0][kk], sacc[0][n], 0, 0, 0); \
    _Pragma("unroll")                                                         \
    for (int kk = 0; kk < 2; ++kk)                                            \
      _Pragma("unroll")                                                       \
      for (int n = 0; n < 4; ++n)                                             \
        sacc[1][n] = __builtin_amdgcn_mfma_f32_16x16x32_f16(kf[kk][n], qf[1][kk], sacc[1][n], 0, 0, 0); \
    __builtin_amdgcn_s_setprio(0);                                            \
    f16x8 vf[2][4];                                                           \
    _Pragma("unroll")                                                         \
    for (int kk = 0; kk < 2; ++kk)                                            \
      _Pragma("unroll")                                                       \
      for (int n = 0; n < 4; ++n)                                             \
        vf[kk][n] = *(const f16x8*)(Vsh[buf] + (n * 16 + l16) * KVB +         \
                                    ((kk * 32 + l4 * 8) ^ ((l16 & 7) * 8)));  \
    f16x8 bfr[2][2];                                                          \
    SOFTMAX(0);          /* overlaps tail of QKT(g1) on MFMA pipe */          \
    __builtin_amdgcn_s_setprio(1);                                            \
    _Pragma("unroll")                                                         \
    for (int kk = 0; kk < 2; ++kk)                                            \
      _Pragma("unroll")                                                       \
      for (int n = 0; n < 4; ++n)                                             \
        oacc[0][n] = __builtin_amdgcn_mfma_f32_16x16x32_f16(vf[kk][n], bfr[0][kk], oacc[0][n], 0, 0, 0); \
    __builtin_amdgcn_s_setprio(0);                                            \
    SOFTMAX(1);          /* overlaps PV(g0) on MFMA pipe */                   \
    __builtin_amdgcn_s_setprio(1);                                            \
    _Pragma("unroll")                                                         \
    for (int kk = 0; kk < 2; ++kk)                                            \
      _Pragma("unroll")                                                       \
      for (int n = 0; n < 4; ++n)                                             \
        oacc[1][n] = __builtin_amdgcn_mfma_f32_16x16x32_f16(vf[kk][n], bfr[1][kk], oacc[1][n], 0, 0, 0); \
    __builtin_amdgcn_s_setprio(0);                                            \
  } while (0)

  STAGE(0, 0);
  __syncthreads();
  for (int t0 = 0; t0 < SQ; t0 += 2 * KVB) {
    STAGE(1, t0 + KVB);
    COMPUTE(0);
    __syncthreads();
    if (t0 + 2 * KVB < SQ) STAGE(0, t0 + 2 * KVB);
    COMPUTE(1);
    __syncthreads();
  }
#undef STAGE
#undef COMPUTE
#undef SOFTMAX

  #pragma unroll
  for (int g = 0; g < 2; ++g) {
    float lt = lrun[g];
    lt += __shfl_xor(lt, 16);
    lt += __shfl_xor(lt, 32);
    float inv = 1.f / lt;
    const int s = s0 + g * 16 + l16;
    f16* obase = O + ((size_t)b * SQ + s) * DQ + h * HD + l4 * 4;
    #pragma unroll
    for (int n = 0; n < 4; ++n) {
      f16x4 ov = { (f16)(oacc[g][n][0] * inv), (f16)(oacc[g][n][1] * inv),
                   (f16)(oacc[g][n][2] * inv), (f16)(oacc[g][n][3] * inv) };
      *(f16x4*)(obase + n * 16) = ov;
    }
  }
}

extern "C" void kernel_launch(void* const* d_in, const int* in_sizes, int n_in,
                              void* d_out, int out_size, void* d_ws, size_t ws_size,
                              hipStream_t stream) {
  const float* x      = (const float*)d_in[0];
  const float* w_qkv  = (const float*)d_in[1];
  const float* b_qkv  = (const float*)d_in[2];
  const float* w_proj = (const float*)d_in[3];
  const float* b_proj = (const float*)d_in[4];
  float* out = (float*)d_out;

  char* ws = (char*)d_ws;
  f16* xh     = (f16*)ws; ws += (size_t)M_TOK * DQ * 2;
  f16* wqkvT  = (f16*)ws; ws += (size_t)3 * DQ * DQ * 2;
  f16* wprojT = (f16*)ws; ws += (size_t)DQ * DQ * 2;
  f16* Qb     = (f16*)ws; ws += (size_t)M_TOK * DQ * 2;
  f16* Kb     = (f16*)ws; ws += (size_t)M_TOK * DQ * 2;
  f16* Vt     = (f16*)ws; ws += (size_t)M_TOK * DQ * 2;
  f16* AO     = xh;  // attn output; xh fully consumed by qkv GEMM before attn

  prep<<<8448, 256, 0, stream>>>(x, xh, w_qkv, wqkvT, w_proj, wprojT);

  gemm128<0><<<(M_TOK / 128) * (3 * DQ / 128), 256, 0, stream>>>(
      xh, wqkvT, b_qkv, nullptr, Qb, Kb, Vt, M_TOK, 3 * DQ, DQ, 3 * DQ / 128);

  attn<<<BQ * HQ * (SQ / 128), 256, 0, stream>>>(Qb, Kb, Vt, AO);

  gemm128<1><<<(M_TOK / 128) * (DQ / 128), 256, 0, stream>>>(
      AO, wprojT, b_proj, out, nullptr, nullptr, nullptr, M_TOK, DQ, DQ, DQ / 128);
}

// Round 16
// 148.796 us; speedup vs baseline: 1.1244x; 1.0080x over previous
//
#include <hip/hip_runtime.h>

// MHA forward: B=4, S=2048, D=768, H=12, Hd=64
// prep -> qkv GEMM (BK=64 swizzled, per-block operand swap: Q/K epilogue
// stores f16x4 via C^T, V normal) -> flash attn (R15) -> proj GEMM (swapped,
// float4 stores).

typedef _Float16 f16;
typedef _Float16 f16x8 __attribute__((ext_vector_type(8)));
typedef _Float16 f16x4 __attribute__((ext_vector_type(4)));
typedef float f32x4 __attribute__((ext_vector_type(4)));

#define BQ 4
#define SQ 2048
#define DQ 768
#define HQ 12
#define HD 64
#define M_TOK (BQ*SQ)      // 8192
#define KVB 64
#define QSCALE 0.18033688f  // 0.125 * log2(e): scores land in exp2 domain
#define THR_LOG2 11.5f      // defer-max threshold (~e^8)

__device__ __forceinline__ void gld_lds16(const f16* g, f16* l) {
  __builtin_amdgcn_global_load_lds((const __attribute__((address_space(1))) void*)g,
                                   (__attribute__((address_space(3))) void*)l,
                                   16, 0, 0);
}

// ---- prep: cvt x (blocks 0..6143), transpose w_qkv (6144..7871), w_proj (7872..8447)
__global__ __launch_bounds__(256)
void prep(const float* __restrict__ x, f16* __restrict__ xh,
          const float* __restrict__ w_qkv, f16* __restrict__ wqkvT,
          const float* __restrict__ w_proj, f16* __restrict__ wprojT)
{
  __shared__ float tile[32][33];
  const int bid = blockIdx.x, tid = threadIdx.x;
  if (bid < 6144) {
    int i = (bid * 256 + tid) * 4;
    float4 v = *(const float4*)(x + i);
    f16x4 o = { (f16)v.x, (f16)v.y, (f16)v.z, (f16)v.w };
    *(f16x4*)(xh + i) = o;
    return;
  }
  const float* w; f16* wt; int K, N, nb, kb;
  if (bid < 7872) {
    int b2 = bid - 6144; w = w_qkv; wt = wqkvT; K = DQ; N = 3 * DQ;
    nb = (b2 % 72) * 32; kb = (b2 / 72) * 32;
  } else {
    int b3 = bid - 7872; w = w_proj; wt = wprojT; K = DQ; N = DQ;
    nb = (b3 % 24) * 32; kb = (b3 / 24) * 32;
  }
  int tx = tid & 31, ty = tid >> 5;
  for (int r = ty; r < 32; r += 8)
    tile[r][tx] = w[(size_t)(kb + r) * N + nb + tx];
  __syncthreads();
  for (int r = ty; r < 32; r += 8)
    wt[(size_t)(nb + r) * K + kb + tx] = (f16)tile[tx][r];
}

// ---- 128x128 tile GEMM, A [M][K] f16, Bt [N][K] f16, BK=64, dbuf, swizzled ----
// MODE 0: qkv. Q/K blocks (cbase/DQ<2): SWAPPED mfma -> C^T, f16x4 stores
//         along hd. V blocks: normal mfma, V^T token-contiguous f16x4.
// MODE 1: proj. SWAPPED mfma, float4 stores.
template<int MODE>
__global__ __launch_bounds__(256, 2)
void gemm128(const f16* __restrict__ A, const f16* __restrict__ Bt,
             const float* __restrict__ bias, float* __restrict__ Cf,
             f16* __restrict__ Qb, f16* __restrict__ Kb, f16* __restrict__ Vt,
             int M, int N, int K, int nbx)
{
  __shared__ f16 Ash[2][128 * 64];   // 2 x 16 KB
  __shared__ f16 Bsh[2][128 * 64];   // 2 x 16 KB
  const int tid = threadIdx.x;
  const int cpx = gridDim.x >> 3;
  const int bid = (blockIdx.x & 7) * cpx + (blockIdx.x >> 3);
  const int nb = bid % nbx, mb = bid / nbx;
  const int m0 = mb * 128, n0 = nb * 128;
  const int lane = tid & 63, wid = tid >> 6;
  const int wr = wid >> 1, wc = wid & 1;
  const int l16 = lane & 15, l4 = lane >> 4;

  f32x4 acc[4][4] = {};

  const f16* aP[4]; const f16* bP[4]; int lOff[4];
  #pragma unroll
  for (int j = 0; j < 4; ++j) {
    int q = j * 256 + tid;
    int r = q >> 3;
    int sc = ((q & 7) ^ (r & 7)) * 8;     // pre-XOR'd source col
    aP[j] = A  + (size_t)(m0 + r) * K + sc;
    bP[j] = Bt + (size_t)(n0 + r) * K + sc;
    lOff[j] = q * 8;
  }

#define GSTAGE(buf, k0)                                   \
  do {                                                    \
    _Pragma("unroll")                                     \
    for (int j = 0; j < 4; ++j) {                         \
      gld_lds16(aP[j] + (k0), Ash[buf] + lOff[j]);        \
      gld_lds16(bP[j] + (k0), Bsh[buf] + lOff[j]);        \
    }                                                     \
  } while (0)

#define KLOOP(SWAPPED)                                                        \
  for (int k0 = 0; k0 < K; k0 += 64) {                                        \
    const int buf = (k0 >> 6) & 1;                                            \
    if (k0 + 64 < K) GSTAGE(buf ^ 1, k0 + 64);                                \
    _Pragma("unroll")                                                         \
    for (int kk = 0; kk < 2; ++kk) {                                          \
      f16x8 af[4], bfr[4];                                                    \
      _Pragma("unroll")                                                       \
      for (int m = 0; m < 4; ++m) {                                           \
        int R = wr * 64 + m * 16 + l16;                                       \
        af[m] = *(const f16x8*)(Ash[buf] + R * 64 + (((kk * 4 + l4) ^ (R & 7)) * 8)); \
      }                                                                       \
      _Pragma("unroll")                                                       \
      for (int n = 0; n < 4; ++n) {                                           \
        int R = wc * 64 + n * 16 + l16;                                       \
        bfr[n] = *(const f16x8*)(Bsh[buf] + R * 64 + (((kk * 4 + l4) ^ (R & 7)) * 8)); \
      }                                                                       \
      _Pragma("unroll")                                                       \
      for (int m = 0; m < 4; ++m)                                             \
        _Pragma("unroll")                                                     \
        for (int n = 0; n < 4; ++n) {                                         \
          if (SWAPPED)                                                        \
            acc[m][n] = __builtin_amdgcn_mfma_f32_16x16x32_f16(bfr[n], af[m], acc[m][n], 0, 0, 0); \
          else                                                                \
            acc[m][n] = __builtin_amdgcn_mfma_f32_16x16x32_f16(af[m], bfr[n], acc[m][n], 0, 0, 0); \
        }                                                                     \
    }                                                                         \
    __syncthreads();                                                          \
  }

  const int cbase = n0 + wc * 64;
  const int rbase = m0 + wr * 64;
  const int which = (MODE == 1) ? 0 : (cbase / DQ);
  const bool swapped = (MODE == 1) || (which < 2);

  GSTAGE(0, 0);
  __syncthreads();
  if (swapped) { KLOOP(true) } else { KLOOP(false) }
#undef KLOOP
#undef GSTAGE

  if (MODE == 1) {
    // swapped: lane owns token s; features c0..c0+3 contiguous -> float4
    #pragma unroll
    for (int n = 0; n < 4; ++n) {
      const int c0 = cbase + n * 16 + l4 * 4;
      const float4 bv = *(const float4*)(bias + c0);
      #pragma unroll
      for (int m = 0; m < 4; ++m) {
        const int s = rbase + m * 16 + l16;
        float4 ov = { acc[m][n][0] + bv.x, acc[m][n][1] + bv.y,
                      acc[m][n][2] + bv.z, acc[m][n][3] + bv.w };
        *(float4*)(Cf + (size_t)s * N + c0) = ov;
      }
    }
  } else if (which < 2) {
    // swapped Q/K: f16x4 along hd
    f16* dst = which ? Kb : Qb;
    const int h = (cbase - which * DQ) >> 6;     // block 64-col aligned
    #pragma unroll
    for (int n = 0; n < 4; ++n) {
      const int c0 = cbase + n * 16 + l4 * 4;
      const float4 bv = *(const float4*)(bias + c0);
      const int hd0 = n * 16 + l4 * 4;           // < 64
      #pragma unroll
      for (int m = 0; m < 4; ++m) {
        const int st = rbase + m * 16 + l16;
        const int b = st >> 11, s = st & 2047;
        const size_t bh = (size_t)(b * HQ + h);
        float v0 = acc[m][n][0] + bv.x, v1 = acc[m][n][1] + bv.y;
        float v2 = acc[m][n][2] + bv.z, v3 = acc[m][n][3] + bv.w;
        if (!which) { v0 *= QSCALE; v1 *= QSCALE; v2 *= QSCALE; v3 *= QSCALE; }
        f16x4 ov = { (f16)v0, (f16)v1, (f16)v2, (f16)v3 };
        *(f16x4*)(dst + (bh * SQ + s) * HD + hd0) = ov;
      }
    }
  } else {
    // V normal: token-contiguous f16x4 into V^T
    #pragma unroll
    for (int n = 0; n < 4; ++n) {
      int c = cbase + n * 16 + l16;
      float bv = bias[c];
      int rem = c - 2 * DQ;
      int h = rem >> 6, hd = rem & 63;
      #pragma unroll
      for (int m = 0; m < 4; ++m) {
        int rr0 = rbase + m * 16 + l4 * 4;
        int b = rr0 >> 11, s = rr0 & 2047;
        size_t bh = (size_t)(b * HQ + h);
        f16x4 ov = { (f16)(acc[m][n][0] + bv), (f16)(acc[m][n][1] + bv),
                     (f16)(acc[m][n][2] + bv), (f16)(acc[m][n][3] + bv) };
        *(f16x4*)(Vt + (bh * HD + hd) * SQ + s) = ov;
      }
    }
  }
}

// K-row permutation (C-slot -> PV B-slot mapping)
__device__ __forceinline__ int permK(int p) {
  return ((p & 16) << 1) | (((p >> 2) & 3) << 3) | ((p & 32) >> 3) | (p & 3);
}

// ---- flash attention (R15: branch-local max-shfl, deferred l-sum) ----
__global__ __launch_bounds__(256, 3)
void attn(const f16* __restrict__ Qb, const f16* __restrict__ Kb,
          const f16* __restrict__ Vt, f16* __restrict__ O)
{
  __shared__ f16 Ksh[2][KVB * HD];
  __shared__ f16 Vsh[2][HD * KVB];
  const int tid = threadIdx.x, lane = tid & 63, wid = tid >> 6;
  const int l16 = lane & 15, l4 = lane >> 4;

  const int nwg = gridDim.x;
  const int cpx = nwg >> 3;
  const int swz = (blockIdx.x & 7) * cpx + (blockIdx.x >> 3);
  const int qt = swz & 15, bh = swz >> 4;
  const int b = bh / HQ, h = bh - b * HQ;
  const f16* q  = Qb + (size_t)bh * SQ * HD;
  const f16* kp = Kb + (size_t)bh * SQ * HD;
  const f16* vp = Vt + (size_t)bh * HD * SQ;
  const int s0 = qt * 128 + wid * 32;

  f16x8 qf[2][2];
  #pragma unroll
  for (int g = 0; g < 2; ++g)
    #pragma unroll
    for (int kk = 0; kk < 2; ++kk)
      qf[g][kk] = *(const f16x8*)(q + (size_t)(s0 + g * 16 + l16) * HD + kk * 32 + l4 * 8);

  f32x4 oacc[2][4] = {};
  float mrun[2] = { -1e30f, -1e30f };
  float lrun[2] = { 0.f, 0.f };        // per-lane partials, row-reduced at end

  const int p0 = tid >> 3, p1 = (tid >> 3) + 32;
  const int scS = ((tid & 7) ^ (p0 & 7)) * 8;
  const int kr0 = permK(p0), kr1 = permK(p1);

#define STAGE(buf, t0)                                                        \
  do {                                                                        \
    gld_lds16(kp + (size_t)((t0) + kr0) * HD + scS, Ksh[buf] + tid * 8);      \
    gld_lds16(kp + (size_t)((t0) + kr1) * HD + scS, Ksh[buf] + (tid + 256) * 8);\
    gld_lds16(vp + (size_t)p0 * SQ + (t0) + scS,   Vsh[buf] + tid * 8);       \
    gld_lds16(vp + (size_t)p1 * SQ + (t0) + scS,   Vsh[buf] + (tid + 256) * 8);\
  } while (0)

#define SOFTMAX(g)                                                            \
  do {                                                                        \
    float rm = -1e30f;                                                        \
    _Pragma("unroll")                                                         \
    for (int n = 0; n < 4; ++n)                                               \
      rm = fmaxf(rm, fmaxf(fmaxf(sacc[g][n][0], sacc[g][n][1]),               \
                           fmaxf(sacc[g][n][2], sacc[g][n][3])));             \
    if (!__all(rm - mrun[g] <= THR_LOG2)) {                                   \
      rm = fmaxf(rm, __shfl_xor(rm, 16));                                     \
      rm = fmaxf(rm, __shfl_xor(rm, 32));                                     \
      float mn = fmaxf(mrun[g], rm);                                          \
      float corr = __builtin_amdgcn_exp2f(mrun[g] - mn);                      \
      lrun[g] *= corr;                                                        \
      _Pragma("unroll")                                                       \
      for (int n = 0; n < 4; ++n)                                             \
        oacc[g][n] *= corr;                                                   \
      mrun[g] = mn;                                                           \
    }                                                                         \
    float mref = mrun[g];                                                     \
    float ps = 0.f;                                                           \
    _Pragma("unroll")                                                         \
    for (int n = 0; n < 4; ++n)                                               \
      _Pragma("unroll")                                                       \
      for (int r = 0; r < 4; ++r) {                                           \
        float pv = __builtin_amdgcn_exp2f(sacc[g][n][r] - mref);              \
        bfr[g][n & 1][(n >> 1) * 4 + r] = (f16)pv;                            \
        ps += pv;                                                             \
      }                                                                       \
    lrun[g] += ps;                                                            \
  } while (0)

#define COMPUTE(buf)                                                          \
  do {                                                                        \
    f32x4 sacc[2][4] = {};                                                    \
    f16x8 kf[2][4];                                                           \
    _Pragma("unroll")                                                         \
    for (int kk = 0; kk < 2; ++kk)                                            \
      _Pragma("unroll")                                                       \
      for (int n = 0; n < 4; ++n)                                             \
        kf[kk][n] = *(const f16x8*)(Ksh[buf] + (n * 16 + l16) * HD +          \
                                    ((kk * 32 + l4 * 8) ^ ((l16 & 7) * 8)));  \
    __builtin_amdgcn_s_setprio(1);                                            \
    _Pragma("unroll")                                                         \
    for (int kk = 0; kk < 2; ++kk)                                            \
      _Pragma("unroll")                                                       \
      for (int n = 0; n < 4; ++n)                                             \
        sacc[0][n] = __builtin_amdgcn_mfma_f32_16x16x32_f16(kf[kk][n], qf[0][kk], sacc[0][n], 0, 0, 0); \
    _Pragma("unroll")                                                         \
    for (int kk = 0; kk < 2; ++kk)                                            \
      _Pragma("unroll")                                                       \
      for (int n = 0; n < 4; ++n)                                             \
        sacc[1][n] = __builtin_amdgcn_mfma_f32_16x16x32_f16(kf[kk][n], qf[1][kk], sacc[1][n], 0, 0, 0); \
    __builtin_amdgcn_s_setprio(0);                                            \
    f16x8 vf[2][4];                                                           \
    _Pragma("unroll")                                                         \
    for (int kk = 0; kk < 2; ++kk)                                            \
      _Pragma("unroll")                                                       \
      for (int n = 0; n < 4; ++n)                                             \
        vf[kk][n] = *(const f16x8*)(Vsh[buf] + (n * 16 + l16) * KVB +         \
                                    ((kk * 32 + l4 * 8) ^ ((l16 & 7) * 8)));  \
    f16x8 bfr[2][2];                                                          \
    SOFTMAX(0);                                                               \
    __builtin_amdgcn_s_setprio(1);                                            \
    _Pragma("unroll")                                                         \
    for (int kk = 0; kk < 2; ++kk)                                            \
      _Pragma("unroll")                                                       \
      for (int n = 0; n < 4; ++n)                                             \
        oacc[0][n] = __builtin_amdgcn_mfma_f32_16x16x32_f16(vf[kk][n], bfr[0][kk], oacc[0][n], 0, 0, 0); \
    __builtin_amdgcn_s_setprio(0);                                            \
    SOFTMAX(1);                                                               \
    __builtin_amdgcn_s_setprio(1);                                            \
    _Pragma("unroll")                                                         \
    for (int kk = 0; kk < 2; ++kk)                                            \
      _Pragma("unroll")                                                       \
      for (int n = 0; n < 4; ++n)                                             \
        oacc[1][n] = __builtin_amdgcn_mfma_f32_16x16x32_f16(vf[kk][n], bfr[1][kk], oacc[1][n], 0, 0, 0); \
    __builtin_amdgcn_s_setprio(0);                                            \
  } while (0)

  STAGE(0, 0);
  __syncthreads();
  for (int t0 = 0; t0 < SQ; t0 += 2 * KVB) {
    STAGE(1, t0 + KVB);
    COMPUTE(0);
    __syncthreads();
    if (t0 + 2 * KVB < SQ) STAGE(0, t0 + 2 * KVB);
    COMPUTE(1);
    __syncthreads();
  }
#undef STAGE
#undef COMPUTE
#undef SOFTMAX

  #pragma unroll
  for (int g = 0; g < 2; ++g) {
    float lt = lrun[g];
    lt += __shfl_xor(lt, 16);
    lt += __shfl_xor(lt, 32);
    float inv = 1.f / lt;
    const int s = s0 + g * 16 + l16;
    f16* obase = O + ((size_t)b * SQ + s) * DQ + h * HD + l4 * 4;
    #pragma unroll
    for (int n = 0; n < 4; ++n) {
      f16x4 ov = { (f16)(oacc[g][n][0] * inv), (f16)(oacc[g][n][1] * inv),
                   (f16)(oacc[g][n][2] * inv), (f16)(oacc[g][n][3] * inv) };
      *(f16x4*)(obase + n * 16) = ov;
    }
  }
}

extern "C" void kernel_launch(void* const* d_in, const int* in_sizes, int n_in,
                              void* d_out, int out_size, void* d_ws, size_t ws_size,
                              hipStream_t stream) {
  const float* x      = (const float*)d_in[0];
  const float* w_qkv  = (const float*)d_in[1];
  const float* b_qkv  = (const float*)d_in[2];
  const float* w_proj = (const float*)d_in[3];
  const float* b_proj = (const float*)d_in[4];
  float* out = (float*)d_out;

  char* ws = (char*)d_ws;
  f16* xh     = (f16*)ws; ws += (size_t)M_TOK * DQ * 2;
  f16* wqkvT  = (f16*)ws; ws += (size_t)3 * DQ * DQ * 2;
  f16* wprojT = (f16*)ws; ws += (size_t)DQ * DQ * 2;
  f16* Qb     = (f16*)ws; ws += (size_t)M_TOK * DQ * 2;
  f16* Kb     = (f16*)ws; ws += (size_t)M_TOK * DQ * 2;
  f16* Vt     = (f16*)ws; ws += (size_t)M_TOK * DQ * 2;
  f16* AO     = xh;  // attn output; xh fully consumed by qkv GEMM before attn

  prep<<<8448, 256, 0, stream>>>(x, xh, w_qkv, wqkvT, w_proj, wprojT);

  gemm128<0><<<(M_TOK / 128) * (3 * DQ / 128), 256, 0, stream>>>(
      xh, wqkvT, b_qkv, nullptr, Qb, Kb, Vt, M_TOK, 3 * DQ, DQ, 3 * DQ / 128);

  attn<<<BQ * HQ * (SQ / 128), 256, 0, stream>>>(Qb, Kb, Vt, AO);

  gemm128<1><<<(M_TOK / 128) * (DQ / 128), 256, 0, stream>>>(
      AO, wprojT, b_proj, out, nullptr, nullptr, nullptr, M_TOK, DQ, DQ, DQ / 128);
}

// Round 17
// 147.043 us; speedup vs baseline: 1.1378x; 1.0119x over previous
//
#include <hip/hip_runtime.h>

// MHA forward: B=4, S=2048, D=768, H=12, Hd=64
// prep -> qkv GEMM (BK=64 swizzled, per-block operand swap) -> flash attn
// (R15) -> proj GEMM (64x128 tile, 3 blocks/CU all-resident, swapped float4).

typedef _Float16 f16;
typedef _Float16 f16x8 __attribute__((ext_vector_type(8)));
typedef _Float16 f16x4 __attribute__((ext_vector_type(4)));
typedef float f32x4 __attribute__((ext_vector_type(4)));

#define BQ 4
#define SQ 2048
#define DQ 768
#define HQ 12
#define HD 64
#define M_TOK (BQ*SQ)      // 8192
#define KVB 64
#define QSCALE 0.18033688f  // 0.125 * log2(e): scores land in exp2 domain
#define THR_LOG2 11.5f      // defer-max threshold (~e^8)

__device__ __forceinline__ void gld_lds16(const f16* g, f16* l) {
  __builtin_amdgcn_global_load_lds((const __attribute__((address_space(1))) void*)g,
                                   (__attribute__((address_space(3))) void*)l,
                                   16, 0, 0);
}

// ---- prep: cvt x (blocks 0..6143), transpose w_qkv (6144..7871), w_proj (7872..8447)
__global__ __launch_bounds__(256)
void prep(const float* __restrict__ x, f16* __restrict__ xh,
          const float* __restrict__ w_qkv, f16* __restrict__ wqkvT,
          const float* __restrict__ w_proj, f16* __restrict__ wprojT)
{
  __shared__ float tile[32][33];
  const int bid = blockIdx.x, tid = threadIdx.x;
  if (bid < 6144) {
    int i = (bid * 256 + tid) * 4;
    float4 v = *(const float4*)(x + i);
    f16x4 o = { (f16)v.x, (f16)v.y, (f16)v.z, (f16)v.w };
    *(f16x4*)(xh + i) = o;
    return;
  }
  const float* w; f16* wt; int K, N, nb, kb;
  if (bid < 7872) {
    int b2 = bid - 6144; w = w_qkv; wt = wqkvT; K = DQ; N = 3 * DQ;
    nb = (b2 % 72) * 32; kb = (b2 / 72) * 32;
  } else {
    int b3 = bid - 7872; w = w_proj; wt = wprojT; K = DQ; N = DQ;
    nb = (b3 % 24) * 32; kb = (b3 / 24) * 32;
  }
  int tx = tid & 31, ty = tid >> 5;
  for (int r = ty; r < 32; r += 8)
    tile[r][tx] = w[(size_t)(kb + r) * N + nb + tx];
  __syncthreads();
  for (int r = ty; r < 32; r += 8)
    wt[(size_t)(nb + r) * K + kb + tx] = (f16)tile[tx][r];
}

// ---- 128x128 tile GEMM (qkv), BK=64, dbuf, swizzled; per-block operand swap
template<int MODE>
__global__ __launch_bounds__(256, 2)
void gemm128(const f16* __restrict__ A, const f16* __restrict__ Bt,
             const float* __restrict__ bias, float* __restrict__ Cf,
             f16* __restrict__ Qb, f16* __restrict__ Kb, f16* __restrict__ Vt,
             int M, int N, int K, int nbx)
{
  __shared__ f16 Ash[2][128 * 64];   // 2 x 16 KB
  __shared__ f16 Bsh[2][128 * 64];   // 2 x 16 KB
  const int tid = threadIdx.x;
  const int cpx = gridDim.x >> 3;
  const int bid = (blockIdx.x & 7) * cpx + (blockIdx.x >> 3);
  const int nb = bid % nbx, mb = bid / nbx;
  const int m0 = mb * 128, n0 = nb * 128;
  const int lane = tid & 63, wid = tid >> 6;
  const int wr = wid >> 1, wc = wid & 1;
  const int l16 = lane & 15, l4 = lane >> 4;

  f32x4 acc[4][4] = {};

  const f16* aP[4]; const f16* bP[4]; int lOff[4];
  #pragma unroll
  for (int j = 0; j < 4; ++j) {
    int q = j * 256 + tid;
    int r = q >> 3;
    int sc = ((q & 7) ^ (r & 7)) * 8;     // pre-XOR'd source col
    aP[j] = A  + (size_t)(m0 + r) * K + sc;
    bP[j] = Bt + (size_t)(n0 + r) * K + sc;
    lOff[j] = q * 8;
  }

#define GSTAGE(buf, k0)                                   \
  do {                                                    \
    _Pragma("unroll")                                     \
    for (int j = 0; j < 4; ++j) {                         \
      gld_lds16(aP[j] + (k0), Ash[buf] + lOff[j]);        \
      gld_lds16(bP[j] + (k0), Bsh[buf] + lOff[j]);        \
    }                                                     \
  } while (0)

#define KLOOP(SWAPPED)                                                        \
  for (int k0 = 0; k0 < K; k0 += 64) {                                        \
    const int buf = (k0 >> 6) & 1;                                            \
    if (k0 + 64 < K) GSTAGE(buf ^ 1, k0 + 64);                                \
    _Pragma("unroll")                                                         \
    for (int kk = 0; kk < 2; ++kk) {                                          \
      f16x8 af[4], bfr[4];                                                    \
      _Pragma("unroll")                                                       \
      for (int m = 0; m < 4; ++m) {                                           \
        int R = wr * 64 + m * 16 + l16;                                       \
        af[m] = *(const f16x8*)(Ash[buf] + R * 64 + (((kk * 4 + l4) ^ (R & 7)) * 8)); \
      }                                                                       \
      _Pragma("unroll")                                                       \
      for (int n = 0; n < 4; ++n) {                                           \
        int R = wc * 64 + n * 16 + l16;                                       \
        bfr[n] = *(const f16x8*)(Bsh[buf] + R * 64 + (((kk * 4 + l4) ^ (R & 7)) * 8)); \
      }                                                                       \
      _Pragma("unroll")                                                       \
      for (int m = 0; m < 4; ++m)                                             \
        _Pragma("unroll")                                                     \
        for (int n = 0; n < 4; ++n) {                                         \
          if (SWAPPED)                                                        \
            acc[m][n] = __builtin_amdgcn_mfma_f32_16x16x32_f16(bfr[n], af[m], acc[m][n], 0, 0, 0); \
          else                                                                \
            acc[m][n] = __builtin_amdgcn_mfma_f32_16x16x32_f16(af[m], bfr[n], acc[m][n], 0, 0, 0); \
        }                                                                     \
    }                                                                         \
    __syncthreads();                                                          \
  }

  const int cbase = n0 + wc * 64;
  const int rbase = m0 + wr * 64;
  const int which = (MODE == 1) ? 0 : (cbase / DQ);
  const bool swapped = (MODE == 1) || (which < 2);

  GSTAGE(0, 0);
  __syncthreads();
  if (swapped) { KLOOP(true) } else { KLOOP(false) }
#undef KLOOP
#undef GSTAGE

  if (MODE == 1) {
    #pragma unroll
    for (int n = 0; n < 4; ++n) {
      const int c0 = cbase + n * 16 + l4 * 4;
      const float4 bv = *(const float4*)(bias + c0);
      #pragma unroll
      for (int m = 0; m < 4; ++m) {
        const int s = rbase + m * 16 + l16;
        float4 ov = { acc[m][n][0] + bv.x, acc[m][n][1] + bv.y,
                      acc[m][n][2] + bv.z, acc[m][n][3] + bv.w };
        *(float4*)(Cf + (size_t)s * N + c0) = ov;
      }
    }
  } else if (which < 2) {
    f16* dst = which ? Kb : Qb;
    const int h = (cbase - which * DQ) >> 6;
    #pragma unroll
    for (int n = 0; n < 4; ++n) {
      const int c0 = cbase + n * 16 + l4 * 4;
      const float4 bv = *(const float4*)(bias + c0);
      const int hd0 = n * 16 + l4 * 4;
      #pragma unroll
      for (int m = 0; m < 4; ++m) {
        const int st = rbase + m * 16 + l16;
        const int b = st >> 11, s = st & 2047;
        const size_t bh = (size_t)(b * HQ + h);
        float v0 = acc[m][n][0] + bv.x, v1 = acc[m][n][1] + bv.y;
        float v2 = acc[m][n][2] + bv.z, v3 = acc[m][n][3] + bv.w;
        if (!which) { v0 *= QSCALE; v1 *= QSCALE; v2 *= QSCALE; v3 *= QSCALE; }
        f16x4 ov = { (f16)v0, (f16)v1, (f16)v2, (f16)v3 };
        *(f16x4*)(dst + (bh * SQ + s) * HD + hd0) = ov;
      }
    }
  } else {
    #pragma unroll
    for (int n = 0; n < 4; ++n) {
      int c = cbase + n * 16 + l16;
      float bv = bias[c];
      int rem = c - 2 * DQ;
      int h = rem >> 6, hd = rem & 63;
      #pragma unroll
      for (int m = 0; m < 4; ++m) {
        int rr0 = rbase + m * 16 + l4 * 4;
        int b = rr0 >> 11, s = rr0 & 2047;
        size_t bh = (size_t)(b * HQ + h);
        f16x4 ov = { (f16)(acc[m][n][0] + bv), (f16)(acc[m][n][1] + bv),
                     (f16)(acc[m][n][2] + bv), (f16)(acc[m][n][3] + bv) };
        *(f16x4*)(Vt + (bh * HD + hd) * SQ + s) = ov;
      }
    }
  }
}

// ---- proj GEMM: 64x128 tile, 4 waves (wave tile 32x64), BK=64 swizzled dbuf.
// LDS 48 KB -> 3 blocks/CU; grid 768 all co-resident (3 waves/SIMD, 2x qkv's).
// Swapped operands -> float4 stores. Same accumulation order as gemm128<1>.
__global__ __launch_bounds__(256, 3)
void gemm_proj(const f16* __restrict__ A, const f16* __restrict__ Bt,
               const float* __restrict__ bias, float* __restrict__ Cf,
               int M, int N, int K, int nbx)
{
  __shared__ f16 Ash[2][64 * 64];    // 2 x 8 KB
  __shared__ f16 Bsh[2][128 * 64];   // 2 x 16 KB
  const int tid = threadIdx.x;
  const int cpx = gridDim.x >> 3;
  const int bid = (blockIdx.x & 7) * cpx + (blockIdx.x >> 3);
  const int nb = bid % nbx, mb = bid / nbx;
  const int m0 = mb * 64, n0 = nb * 128;
  const int lane = tid & 63, wid = tid >> 6;
  const int wr = wid >> 1, wc = wid & 1;
  const int l16 = lane & 15, l4 = lane >> 4;

  f32x4 acc[2][4] = {};

  const f16* aP[2]; int aOff[2];
  const f16* bP[4]; int bOff[4];
  #pragma unroll
  for (int j = 0; j < 2; ++j) {
    int q = j * 256 + tid;
    int r = q >> 3;
    int sc = ((q & 7) ^ (r & 7)) * 8;
    aP[j] = A + (size_t)(m0 + r) * K + sc;
    aOff[j] = q * 8;
  }
  #pragma unroll
  for (int j = 0; j < 4; ++j) {
    int q = j * 256 + tid;
    int r = q >> 3;
    int sc = ((q & 7) ^ (r & 7)) * 8;
    bP[j] = Bt + (size_t)(n0 + r) * K + sc;
    bOff[j] = q * 8;
  }

#define PSTAGE(buf, k0)                                   \
  do {                                                    \
    _Pragma("unroll")                                     \
    for (int j = 0; j < 2; ++j)                           \
      gld_lds16(aP[j] + (k0), Ash[buf] + aOff[j]);        \
    _Pragma("unroll")                                     \
    for (int j = 0; j < 4; ++j)                           \
      gld_lds16(bP[j] + (k0), Bsh[buf] + bOff[j]);        \
  } while (0)

  PSTAGE(0, 0);
  __syncthreads();
  for (int k0 = 0; k0 < K; k0 += 64) {
    const int buf = (k0 >> 6) & 1;
    if (k0 + 64 < K) PSTAGE(buf ^ 1, k0 + 64);
    #pragma unroll
    for (int kk = 0; kk < 2; ++kk) {
      f16x8 af[2], bfr[4];
      #pragma unroll
      for (int m = 0; m < 2; ++m) {
        int R = wr * 32 + m * 16 + l16;
        af[m] = *(const f16x8*)(Ash[buf] + R * 64 + (((kk * 4 + l4) ^ (R & 7)) * 8));
      }
      #pragma unroll
      for (int n = 0; n < 4; ++n) {
        int R = wc * 64 + n * 16 + l16;
        bfr[n] = *(const f16x8*)(Bsh[buf] + R * 64 + (((kk * 4 + l4) ^ (R & 7)) * 8));
      }
      #pragma unroll
      for (int m = 0; m < 2; ++m)
        #pragma unroll
        for (int n = 0; n < 4; ++n)
          acc[m][n] = __builtin_amdgcn_mfma_f32_16x16x32_f16(bfr[n], af[m], acc[m][n], 0, 0, 0);
    }
    __syncthreads();
  }
#undef PSTAGE

  const int cbase = n0 + wc * 64;
  const int rbase = m0 + wr * 32;
  #pragma unroll
  for (int n = 0; n < 4; ++n) {
    const int c0 = cbase + n * 16 + l4 * 4;
    const float4 bv = *(const float4*)(bias + c0);
    #pragma unroll
    for (int m = 0; m < 2; ++m) {
      const int s = rbase + m * 16 + l16;
      float4 ov = { acc[m][n][0] + bv.x, acc[m][n][1] + bv.y,
                    acc[m][n][2] + bv.z, acc[m][n][3] + bv.w };
      *(float4*)(Cf + (size_t)s * N + c0) = ov;
    }
  }
}

// K-row permutation (C-slot -> PV B-slot mapping)
__device__ __forceinline__ int permK(int p) {
  return ((p & 16) << 1) | (((p >> 2) & 3) << 3) | ((p & 32) >> 3) | (p & 3);
}

// ---- flash attention (R15: branch-local max-shfl, deferred l-sum) ----
__global__ __launch_bounds__(256, 3)
void attn(const f16* __restrict__ Qb, const f16* __restrict__ Kb,
          const f16* __restrict__ Vt, f16* __restrict__ O)
{
  __shared__ f16 Ksh[2][KVB * HD];
  __shared__ f16 Vsh[2][HD * KVB];
  const int tid = threadIdx.x, lane = tid & 63, wid = tid >> 6;
  const int l16 = lane & 15, l4 = lane >> 4;

  const int nwg = gridDim.x;
  const int cpx = nwg >> 3;
  const int swz = (blockIdx.x & 7) * cpx + (blockIdx.x >> 3);
  const int qt = swz & 15, bh = swz >> 4;
  const int b = bh / HQ, h = bh - b * HQ;
  const f16* q  = Qb + (size_t)bh * SQ * HD;
  const f16* kp = Kb + (size_t)bh * SQ * HD;
  const f16* vp = Vt + (size_t)bh * HD * SQ;
  const int s0 = qt * 128 + wid * 32;

  f16x8 qf[2][2];
  #pragma unroll
  for (int g = 0; g < 2; ++g)
    #pragma unroll
    for (int kk = 0; kk < 2; ++kk)
      qf[g][kk] = *(const f16x8*)(q + (size_t)(s0 + g * 16 + l16) * HD + kk * 32 + l4 * 8);

  f32x4 oacc[2][4] = {};
  float mrun[2] = { -1e30f, -1e30f };
  float lrun[2] = { 0.f, 0.f };        // per-lane partials, row-reduced at end

  const int p0 = tid >> 3, p1 = (tid >> 3) + 32;
  const int scS = ((tid & 7) ^ (p0 & 7)) * 8;
  const int kr0 = permK(p0), kr1 = permK(p1);

#define STAGE(buf, t0)                                                        \
  do {                                                                        \
    gld_lds16(kp + (size_t)((t0) + kr0) * HD + scS, Ksh[buf] + tid * 8);      \
    gld_lds16(kp + (size_t)((t0) + kr1) * HD + scS, Ksh[buf] + (tid + 256) * 8);\
    gld_lds16(vp + (size_t)p0 * SQ + (t0) + scS,   Vsh[buf] + tid * 8);       \
    gld_lds16(vp + (size_t)p1 * SQ + (t0) + scS,   Vsh[buf] + (tid + 256) * 8);\
  } while (0)

#define SOFTMAX(g)                                                            \
  do {                                                                        \
    float rm = -1e30f;                                                        \
    _Pragma("unroll")                                                         \
    for (int n = 0; n < 4; ++n)                                               \
      rm = fmaxf(rm, fmaxf(fmaxf(sacc[g][n][0], sacc[g][n][1]),               \
                           fmaxf(sacc[g][n][2], sacc[g][n][3])));             \
    if (!__all(rm - mrun[g] <= THR_LOG2)) {                                   \
      rm = fmaxf(rm, __shfl_xor(rm, 16));                                     \
      rm = fmaxf(rm, __shfl_xor(rm, 32));                                     \
      float mn = fmaxf(mrun[g], rm);                                          \
      float corr = __builtin_amdgcn_exp2f(mrun[g] - mn);                      \
      lrun[g] *= corr;                                                        \
      _Pragma("unroll")                                                       \
      for (int n = 0; n < 4; ++n)                                             \
        oacc[g][n] *= corr;                                                   \
      mrun[g] = mn;                                                           \
    }                                                                         \
    float mref = mrun[g];                                                     \
    float ps = 0.f;                                                           \
    _Pragma("unroll")                                                         \
    for (int n = 0; n < 4; ++n)                                               \
      _Pragma("unroll")                                                       \
      for (int r = 0; r < 4; ++r) {                                           \
        float pv = __builtin_amdgcn_exp2f(sacc[g][n][r] - mref);              \
        bfr[g][n & 1][(n >> 1) * 4 + r] = (f16)pv;                            \
        ps += pv;                                                             \
      }                                                                       \
    lrun[g] += ps;                                                            \
  } while (0)

#define COMPUTE(buf)                                                          \
  do {                                                                        \
    f32x4 sacc[2][4] = {};                                                    \
    f16x8 kf[2][4];                                                           \
    _Pragma("unroll")                                                         \
    for (int kk = 0; kk < 2; ++kk)                                            \
      _Pragma("unroll")                                                       \
      for (int n = 0; n < 4; ++n)                                             \
        kf[kk][n] = *(const f16x8*)(Ksh[buf] + (n * 16 + l16) * HD +          \
                                    ((kk * 32 + l4 * 8) ^ ((l16 & 7) * 8)));  \
    __builtin_amdgcn_s_setprio(1);                                            \
    _Pragma("unroll")                                                         \
    for (int kk = 0; kk < 2; ++kk)                                            \
      _Pragma("unroll")                                                       \
      for (int n = 0; n < 4; ++n)                                             \
        sacc[0][n] = __builtin_amdgcn_mfma_f32_16x16x32_f16(kf[kk][n], qf[0][kk], sacc[0][n], 0, 0, 0); \
    _Pragma("unroll")                                                         \
    for (int kk = 0; kk < 2; ++kk)                                            \
      _Pragma("unroll")                                                       \
      for (int n = 0; n < 4; ++n)                                             \
        sacc[1][n] = __builtin_amdgcn_mfma_f32_16x16x32_f16(kf[kk][n], qf[1][kk], sacc[1][n], 0, 0, 0); \
    __builtin_amdgcn_s_setprio(0);                                            \
    f16x8 vf[2][4];                                                           \
    _Pragma("unroll")                                                         \
    for (int kk = 0; kk < 2; ++kk)                                            \
      _Pragma("unroll")                                                       \
      for (int n = 0; n < 4; ++n)                                             \
        vf[kk][n] = *(const f16x8*)(Vsh[buf] + (n * 16 + l16) * KVB +         \
                                    ((kk * 32 + l4 * 8) ^ ((l16 & 7) * 8)));  \
    f16x8 bfr[2][2];                                                          \
    SOFTMAX(0);                                                               \
    __builtin_amdgcn_s_setprio(1);                                            \
    _Pragma("unroll")                                                         \
    for (int kk = 0; kk < 2; ++kk)                                            \
      _Pragma("unroll")                                                       \
      for (int n = 0; n < 4; ++n)                                             \
        oacc[0][n] = __builtin_amdgcn_mfma_f32_16x16x32_f16(vf[kk][n], bfr[0][kk], oacc[0][n], 0, 0, 0); \
    __builtin_amdgcn_s_setprio(0);                                            \
    SOFTMAX(1);                                                               \
    __builtin_amdgcn_s_setprio(1);                                            \
    _Pragma("unroll")                                                         \
    for (int kk = 0; kk < 2; ++kk)                                            \
      _Pragma("unroll")                                                       \
      for (int n = 0; n < 4; ++n)                                             \
        oacc[1][n] = __builtin_amdgcn_mfma_f32_16x16x32_f16(vf[kk][n], bfr[1][kk], oacc[1][n], 0, 0, 0); \
    __builtin_amdgcn_s_setprio(0);                                            \
  } while (0)

  STAGE(0, 0);
  __syncthreads();
  for (int t0 = 0; t0 < SQ; t0 += 2 * KVB) {
    STAGE(1, t0 + KVB);
    COMPUTE(0);
    __syncthreads();
    if (t0 + 2 * KVB < SQ) STAGE(0, t0 + 2 * KVB);
    COMPUTE(1);
    __syncthreads();
  }
#undef STAGE
#undef COMPUTE
#undef SOFTMAX

  #pragma unroll
  for (int g = 0; g < 2; ++g) {
    float lt = lrun[g];
    lt += __shfl_xor(lt, 16);
    lt += __shfl_xor(lt, 32);
    float inv = 1.f / lt;
    const int s = s0 + g * 16 + l16;
    f16* obase = O + ((size_t)b * SQ + s) * DQ + h * HD + l4 * 4;
    #pragma unroll
    for (int n = 0; n < 4; ++n) {
      f16x4 ov = { (f16)(oacc[g][n][0] * inv), (f16)(oacc[g][n][1] * inv),
                   (f16)(oacc[g][n][2] * inv), (f16)(oacc[g][n][3] * inv) };
      *(f16x4*)(obase + n * 16) = ov;
    }
  }
}

extern "C" void kernel_launch(void* const* d_in, const int* in_sizes, int n_in,
                              void* d_out, int out_size, void* d_ws, size_t ws_size,
                              hipStream_t stream) {
  const float* x      = (const float*)d_in[0];
  const float* w_qkv  = (const float*)d_in[1];
  const float* b_qkv  = (const float*)d_in[2];
  const float* w_proj = (const float*)d_in[3];
  const float* b_proj = (const float*)d_in[4];
  float* out = (float*)d_out;

  char* ws = (char*)d_ws;
  f16* xh     = (f16*)ws; ws += (size_t)M_TOK * DQ * 2;
  f16* wqkvT  = (f16*)ws; ws += (size_t)3 * DQ * DQ * 2;
  f16* wprojT = (f16*)ws; ws += (size_t)DQ * DQ * 2;
  f16* Qb     = (f16*)ws; ws += (size_t)M_TOK * DQ * 2;
  f16* Kb     = (f16*)ws; ws += (size_t)M_TOK * DQ * 2;
  f16* Vt     = (f16*)ws; ws += (size_t)M_TOK * DQ * 2;
  f16* AO     = xh;  // attn output; xh fully consumed by qkv GEMM before attn

  prep<<<8448, 256, 0, stream>>>(x, xh, w_qkv, wqkvT, w_proj, wprojT);

  gemm128<0><<<(M_TOK / 128) * (3 * DQ / 128), 256, 0, stream>>>(
      xh, wqkvT, b_qkv, nullptr, Qb, Kb, Vt, M_TOK, 3 * DQ, DQ, 3 * DQ / 128);

  attn<<<BQ * HQ * (SQ / 128), 256, 0, stream>>>(Qb, Kb, Vt, AO);

  gemm_proj<<<(M_TOK / 64) * (DQ / 128), 256, 0, stream>>>(
      AO, wprojT, b_proj, out, M_TOK, DQ, DQ, DQ / 128);
}

// Round 18
// 143.391 us; speedup vs baseline: 1.1668x; 1.0255x over previous
//
#include <hip/hip_runtime.h>

// MHA forward: B=4, S=2048, D=768, H=12, Hd=64
// prep -> qkv GEMM (64x128 tile, 3 blocks/CU, BK=64 swizzled, per-block
// operand swap) -> flash attn (R15) -> proj GEMM (same 64x128 structure).

typedef _Float16 f16;
typedef _Float16 f16x8 __attribute__((ext_vector_type(8)));
typedef _Float16 f16x4 __attribute__((ext_vector_type(4)));
typedef float f32x4 __attribute__((ext_vector_type(4)));

#define BQ 4
#define SQ 2048
#define DQ 768
#define HQ 12
#define HD 64
#define M_TOK (BQ*SQ)      // 8192
#define KVB 64
#define QSCALE 0.18033688f  // 0.125 * log2(e): scores land in exp2 domain
#define THR_LOG2 11.5f      // defer-max threshold (~e^8)

__device__ __forceinline__ void gld_lds16(const f16* g, f16* l) {
  __builtin_amdgcn_global_load_lds((const __attribute__((address_space(1))) void*)g,
                                   (__attribute__((address_space(3))) void*)l,
                                   16, 0, 0);
}

// ---- prep: cvt x (blocks 0..6143), transpose w_qkv (6144..7871), w_proj (7872..8447)
__global__ __launch_bounds__(256)
void prep(const float* __restrict__ x, f16* __restrict__ xh,
          const float* __restrict__ w_qkv, f16* __restrict__ wqkvT,
          const float* __restrict__ w_proj, f16* __restrict__ wprojT)
{
  __shared__ float tile[32][33];
  const int bid = blockIdx.x, tid = threadIdx.x;
  if (bid < 6144) {
    int i = (bid * 256 + tid) * 4;
    float4 v = *(const float4*)(x + i);
    f16x4 o = { (f16)v.x, (f16)v.y, (f16)v.z, (f16)v.w };
    *(f16x4*)(xh + i) = o;
    return;
  }
  const float* w; f16* wt; int K, N, nb, kb;
  if (bid < 7872) {
    int b2 = bid - 6144; w = w_qkv; wt = wqkvT; K = DQ; N = 3 * DQ;
    nb = (b2 % 72) * 32; kb = (b2 / 72) * 32;
  } else {
    int b3 = bid - 7872; w = w_proj; wt = wprojT; K = DQ; N = DQ;
    nb = (b3 % 24) * 32; kb = (b3 / 24) * 32;
  }
  int tx = tid & 31, ty = tid >> 5;
  for (int r = ty; r < 32; r += 8)
    tile[r][tx] = w[(size_t)(kb + r) * N + nb + tx];
  __syncthreads();
  for (int r = ty; r < 32; r += 8)
    wt[(size_t)(nb + r) * K + kb + tx] = (f16)tile[tx][r];
}

// ---- 64x128 tile GEMM, 4 waves (wave tile 32x64), BK=64 swizzled dbuf.
// LDS 48 KB -> 3 blocks/CU. MODE 0: qkv (per-block operand swap; Q/K swapped
// f16x4 scatter, V normal f16x4 into V^T). MODE 1: proj (swapped, float4).
template<int MODE>
__global__ __launch_bounds__(256, 3)
void gemm64(const f16* __restrict__ A, const f16* __restrict__ Bt,
            const float* __restrict__ bias, float* __restrict__ Cf,
            f16* __restrict__ Qb, f16* __restrict__ Kb, f16* __restrict__ Vt,
            int M, int N, int K, int nbx)
{
  __shared__ f16 Ash[2][64 * 64];    // 2 x 8 KB
  __shared__ f16 Bsh[2][128 * 64];   // 2 x 16 KB
  const int tid = threadIdx.x;
  const int cpx = gridDim.x >> 3;
  const int bid = (blockIdx.x & 7) * cpx + (blockIdx.x >> 3);
  const int nb = bid % nbx, mb = bid / nbx;
  const int m0 = mb * 64, n0 = nb * 128;
  const int lane = tid & 63, wid = tid >> 6;
  const int wr = wid >> 1, wc = wid & 1;
  const int l16 = lane & 15, l4 = lane >> 4;

  f32x4 acc[2][4] = {};

  const f16* aP[2]; int aOff[2];
  const f16* bP[4]; int bOff[4];
  #pragma unroll
  for (int j = 0; j < 2; ++j) {
    int q = j * 256 + tid;
    int r = q >> 3;
    int sc = ((q & 7) ^ (r & 7)) * 8;
    aP[j] = A + (size_t)(m0 + r) * K + sc;
    aOff[j] = q * 8;
  }
  #pragma unroll
  for (int j = 0; j < 4; ++j) {
    int q = j * 256 + tid;
    int r = q >> 3;
    int sc = ((q & 7) ^ (r & 7)) * 8;
    bP[j] = Bt + (size_t)(n0 + r) * K + sc;
    bOff[j] = q * 8;
  }

#define PSTAGE(buf, k0)                                   \
  do {                                                    \
    _Pragma("unroll")                                     \
    for (int j = 0; j < 2; ++j)                           \
      gld_lds16(aP[j] + (k0), Ash[buf] + aOff[j]);        \
    _Pragma("unroll")                                     \
    for (int j = 0; j < 4; ++j)                           \
      gld_lds16(bP[j] + (k0), Bsh[buf] + bOff[j]);        \
  } while (0)

#define KLOOP(SWAPPED)                                                        \
  for (int k0 = 0; k0 < K; k0 += 64) {                                        \
    const int buf = (k0 >> 6) & 1;                                            \
    if (k0 + 64 < K) PSTAGE(buf ^ 1, k0 + 64);                                \
    _Pragma("unroll")                                                         \
    for (int kk = 0; kk < 2; ++kk) {                                          \
      f16x8 af[2], bfr[4];                                                    \
      _Pragma("unroll")                                                       \
      for (int m = 0; m < 2; ++m) {                                           \
        int R = wr * 32 + m * 16 + l16;                                       \
        af[m] = *(const f16x8*)(Ash[buf] + R * 64 + (((kk * 4 + l4) ^ (R & 7)) * 8)); \
      }                                                                       \
      _Pragma("unroll")                                                       \
      for (int n = 0; n < 4; ++n) {                                           \
        int R = wc * 64 + n * 16 + l16;                                       \
        bfr[n] = *(const f16x8*)(Bsh[buf] + R * 64 + (((kk * 4 + l4) ^ (R & 7)) * 8)); \
      }                                                                       \
      _Pragma("unroll")                                                       \
      for (int m = 0; m < 2; ++m)                                             \
        _Pragma("unroll")                                                     \
        for (int n = 0; n < 4; ++n) {                                         \
          if (SWAPPED)                                                        \
            acc[m][n] = __builtin_amdgcn_mfma_f32_16x16x32_f16(bfr[n], af[m], acc[m][n], 0, 0, 0); \
          else                                                                \
            acc[m][n] = __builtin_amdgcn_mfma_f32_16x16x32_f16(af[m], bfr[n], acc[m][n], 0, 0, 0); \
        }                                                                     \
    }                                                                         \
    __syncthreads();                                                          \
  }

  const int cbase = n0 + wc * 64;
  const int rbase = m0 + wr * 32;
  const int which = (MODE == 1) ? 0 : (cbase / DQ);
  const bool swapped = (MODE == 1) || (which < 2);

  PSTAGE(0, 0);
  __syncthreads();
  if (swapped) { KLOOP(true) } else { KLOOP(false) }
#undef KLOOP
#undef PSTAGE

  if (MODE == 1) {
    #pragma unroll
    for (int n = 0; n < 4; ++n) {
      const int c0 = cbase + n * 16 + l4 * 4;
      const float4 bv = *(const float4*)(bias + c0);
      #pragma unroll
      for (int m = 0; m < 2; ++m) {
        const int s = rbase + m * 16 + l16;
        float4 ov = { acc[m][n][0] + bv.x, acc[m][n][1] + bv.y,
                      acc[m][n][2] + bv.z, acc[m][n][3] + bv.w };
        *(float4*)(Cf + (size_t)s * N + c0) = ov;
      }
    }
  } else if (which < 2) {
    f16* dst = which ? Kb : Qb;
    const int h = (cbase - which * DQ) >> 6;
    #pragma unroll
    for (int n = 0; n < 4; ++n) {
      const int c0 = cbase + n * 16 + l4 * 4;
      const float4 bv = *(const float4*)(bias + c0);
      const int hd0 = n * 16 + l4 * 4;
      #pragma unroll
      for (int m = 0; m < 2; ++m) {
        const int st = rbase + m * 16 + l16;
        const int b = st >> 11, s = st & 2047;
        const size_t bh = (size_t)(b * HQ + h);
        float v0 = acc[m][n][0] + bv.x, v1 = acc[m][n][1] + bv.y;
        float v2 = acc[m][n][2] + bv.z, v3 = acc[m][n][3] + bv.w;
        if (!which) { v0 *= QSCALE; v1 *= QSCALE; v2 *= QSCALE; v3 *= QSCALE; }
        f16x4 ov = { (f16)v0, (f16)v1, (f16)v2, (f16)v3 };
        *(f16x4*)(dst + (bh * SQ + s) * HD + hd0) = ov;
      }
    }
  } else {
    #pragma unroll
    for (int n = 0; n < 4; ++n) {
      int c = cbase + n * 16 + l16;
      float bv = bias[c];
      int rem = c - 2 * DQ;
      int h = rem >> 6, hd = rem & 63;
      #pragma unroll
      for (int m = 0; m < 2; ++m) {
        int rr0 = rbase + m * 16 + l4 * 4;
        int b = rr0 >> 11, s = rr0 & 2047;
        size_t bh = (size_t)(b * HQ + h);
        f16x4 ov = { (f16)(acc[m][n][0] + bv), (f16)(acc[m][n][1] + bv),
                     (f16)(acc[m][n][2] + bv), (f16)(acc[m][n][3] + bv) };
        *(f16x4*)(Vt + (bh * HD + hd) * SQ + s) = ov;
      }
    }
  }
}

// K-row permutation (C-slot -> PV B-slot mapping)
__device__ __forceinline__ int permK(int p) {
  return ((p & 16) << 1) | (((p >> 2) & 3) << 3) | ((p & 32) >> 3) | (p & 3);
}

// ---- flash attention (R15: branch-local max-shfl, deferred l-sum) ----
__global__ __launch_bounds__(256, 3)
void attn(const f16* __restrict__ Qb, const f16* __restrict__ Kb,
          const f16* __restrict__ Vt, f16* __restrict__ O)
{
  __shared__ f16 Ksh[2][KVB * HD];
  __shared__ f16 Vsh[2][HD * KVB];
  const int tid = threadIdx.x, lane = tid & 63, wid = tid >> 6;
  const int l16 = lane & 15, l4 = lane >> 4;

  const int nwg = gridDim.x;
  const int cpx = nwg >> 3;
  const int swz = (blockIdx.x & 7) * cpx + (blockIdx.x >> 3);
  const int qt = swz & 15, bh = swz >> 4;
  const int b = bh / HQ, h = bh - b * HQ;
  const f16* q  = Qb + (size_t)bh * SQ * HD;
  const f16* kp = Kb + (size_t)bh * SQ * HD;
  const f16* vp = Vt + (size_t)bh * HD * SQ;
  const int s0 = qt * 128 + wid * 32;

  f16x8 qf[2][2];
  #pragma unroll
  for (int g = 0; g < 2; ++g)
    #pragma unroll
    for (int kk = 0; kk < 2; ++kk)
      qf[g][kk] = *(const f16x8*)(q + (size_t)(s0 + g * 16 + l16) * HD + kk * 32 + l4 * 8);

  f32x4 oacc[2][4] = {};
  float mrun[2] = { -1e30f, -1e30f };
  float lrun[2] = { 0.f, 0.f };        // per-lane partials, row-reduced at end

  const int p0 = tid >> 3, p1 = (tid >> 3) + 32;
  const int scS = ((tid & 7) ^ (p0 & 7)) * 8;
  const int kr0 = permK(p0), kr1 = permK(p1);

#define STAGE(buf, t0)                                                        \
  do {                                                                        \
    gld_lds16(kp + (size_t)((t0) + kr0) * HD + scS, Ksh[buf] + tid * 8);      \
    gld_lds16(kp + (size_t)((t0) + kr1) * HD + scS, Ksh[buf] + (tid + 256) * 8);\
    gld_lds16(vp + (size_t)p0 * SQ + (t0) + scS,   Vsh[buf] + tid * 8);       \
    gld_lds16(vp + (size_t)p1 * SQ + (t0) + scS,   Vsh[buf] + (tid + 256) * 8);\
  } while (0)

#define SOFTMAX(g)                                                            \
  do {                                                                        \
    float rm = -1e30f;                                                        \
    _Pragma("unroll")                                                         \
    for (int n = 0; n < 4; ++n)                                               \
      rm = fmaxf(rm, fmaxf(fmaxf(sacc[g][n][0], sacc[g][n][1]),               \
                           fmaxf(sacc[g][n][2], sacc[g][n][3])));             \
    if (!__all(rm - mrun[g] <= THR_LOG2)) {                                   \
      rm = fmaxf(rm, __shfl_xor(rm, 16));                                     \
      rm = fmaxf(rm, __shfl_xor(rm, 32));                                     \
      float mn = fmaxf(mrun[g], rm);                                          \
      float corr = __builtin_amdgcn_exp2f(mrun[g] - mn);                      \
      lrun[g] *= corr;                                                        \
      _Pragma("unroll")                                                       \
      for (int n = 0; n < 4; ++n)                                             \
        oacc[g][n] *= corr;                                                   \
      mrun[g] = mn;                                                           \
    }                                                                         \
    float mref = mrun[g];                                                     \
    float ps = 0.f;                                                           \
    _Pragma("unroll")                                                         \
    for (int n = 0; n < 4; ++n)                                               \
      _Pragma("unroll")                                                       \
      for (int r = 0; r < 4; ++r) {                                           \
        float pv = __builtin_amdgcn_exp2f(sacc[g][n][r] - mref);              \
        bfr[g][n & 1][(n >> 1) * 4 + r] = (f16)pv;                            \
        ps += pv;                                                             \
      }                                                                       \
    lrun[g] += ps;                                                            \
  } while (0)

#define COMPUTE(buf)                                                          \
  do {                                                                        \
    f32x4 sacc[2][4] = {};                                                    \
    f16x8 kf[2][4];                                                           \
    _Pragma("unroll")                                                         \
    for (int kk = 0; kk < 2; ++kk)                                            \
      _Pragma("unroll")                                                       \
      for (int n = 0; n < 4; ++n)                                             \
        kf[kk][n] = *(const f16x8*)(Ksh[buf] + (n * 16 + l16) * HD +          \
                                    ((kk * 32 + l4 * 8) ^ ((l16 & 7) * 8)));  \
    __builtin_amdgcn_s_setprio(1);                                            \
    _Pragma("unroll")                                                         \
    for (int kk = 0; kk < 2; ++kk)                                            \
      _Pragma("unroll")                                                       \
      for (int n = 0; n < 4; ++n)                                             \
        sacc[0][n] = __builtin_amdgcn_mfma_f32_16x16x32_f16(kf[kk][n], qf[0][kk], sacc[0][n], 0, 0, 0); \
    _Pragma("unroll")                                                         \
    for (int kk = 0; kk < 2; ++kk)                                            \
      _Pragma("unroll")                                                       \
      for (int n = 0; n < 4; ++n)                                             \
        sacc[1][n] = __builtin_amdgcn_mfma_f32_16x16x32_f16(kf[kk][n], qf[1][kk], sacc[1][n], 0, 0, 0); \
    __builtin_amdgcn_s_setprio(0);                                            \
    f16x8 vf[2][4];                                                           \
    _Pragma("unroll")                                                         \
    for (int kk = 0; kk < 2; ++kk)                                            \
      _Pragma("unroll")                                                       \
      for (int n = 0; n < 4; ++n)                                             \
        vf[kk][n] = *(const f16x8*)(Vsh[buf] + (n * 16 + l16) * KVB +         \
                                    ((kk * 32 + l4 * 8) ^ ((l16 & 7) * 8)));  \
    f16x8 bfr[2][2];                                                          \
    SOFTMAX(0);                                                               \
    __builtin_amdgcn_s_setprio(1);                                            \
    _Pragma("unroll")                                                         \
    for (int kk = 0; kk < 2; ++kk)                                            \
      _Pragma("unroll")                                                       \
      for (int n = 0; n < 4; ++n)                                             \
        oacc[0][n] = __builtin_amdgcn_mfma_f32_16x16x32_f16(vf[kk][n], bfr[0][kk], oacc[0][n], 0, 0, 0); \
    __builtin_amdgcn_s_setprio(0);                                            \
    SOFTMAX(1);                                                               \
    __builtin_amdgcn_s_setprio(1);                                            \
    _Pragma("unroll")                                                         \
    for (int kk = 0; kk < 2; ++kk)                                            \
      _Pragma("unroll")                                                       \
      for (int n = 0; n < 4; ++n)                                             \
        oacc[1][n] = __builtin_amdgcn_mfma_f32_16x16x32_f16(vf[kk][n], bfr[1][kk], oacc[1][n], 0, 0, 0); \
    __builtin_amdgcn_s_setprio(0);                                            \
  } while (0)

  STAGE(0, 0);
  __syncthreads();
  for (int t0 = 0; t0 < SQ; t0 += 2 * KVB) {
    STAGE(1, t0 + KVB);
    COMPUTE(0);
    __syncthreads();
    if (t0 + 2 * KVB < SQ) STAGE(0, t0 + 2 * KVB);
    COMPUTE(1);
    __syncthreads();
  }
#undef STAGE
#undef COMPUTE
#undef SOFTMAX

  #pragma unroll
  for (int g = 0; g < 2; ++g) {
    float lt = lrun[g];
    lt += __shfl_xor(lt, 16);
    lt += __shfl_xor(lt, 32);
    float inv = 1.f / lt;
    const int s = s0 + g * 16 + l16;
    f16* obase = O + ((size_t)b * SQ + s) * DQ + h * HD + l4 * 4;
    #pragma unroll
    for (int n = 0; n < 4; ++n) {
      f16x4 ov = { (f16)(oacc[g][n][0] * inv), (f16)(oacc[g][n][1] * inv),
                   (f16)(oacc[g][n][2] * inv), (f16)(oacc[g][n][3] * inv) };
      *(f16x4*)(obase + n * 16) = ov;
    }
  }
}

extern "C" void kernel_launch(void* const* d_in, const int* in_sizes, int n_in,
                              void* d_out, int out_size, void* d_ws, size_t ws_size,
                              hipStream_t stream) {
  const float* x      = (const float*)d_in[0];
  const float* w_qkv  = (const float*)d_in[1];
  const float* b_qkv  = (const float*)d_in[2];
  const float* w_proj = (const float*)d_in[3];
  const float* b_proj = (const float*)d_in[4];
  float* out = (float*)d_out;

  char* ws = (char*)d_ws;
  f16* xh     = (f16*)ws; ws += (size_t)M_TOK * DQ * 2;
  f16* wqkvT  = (f16*)ws; ws += (size_t)3 * DQ * DQ * 2;
  f16* wprojT = (f16*)ws; ws += (size_t)DQ * DQ * 2;
  f16* Qb     = (f16*)ws; ws += (size_t)M_TOK * DQ * 2;
  f16* Kb     = (f16*)ws; ws += (size_t)M_TOK * DQ * 2;
  f16* Vt     = (f16*)ws; ws += (size_t)M_TOK * DQ * 2;
  f16* AO     = xh;  // attn output; xh fully consumed by qkv GEMM before attn

  prep<<<8448, 256, 0, stream>>>(x, xh, w_qkv, wqkvT, w_proj, wprojT);

  gemm64<0><<<(M_TOK / 64) * (3 * DQ / 128), 256, 0, stream>>>(
      xh, wqkvT, b_qkv, nullptr, Qb, Kb, Vt, M_TOK, 3 * DQ, DQ, 3 * DQ / 128);

  attn<<<BQ * HQ * (SQ / 128), 256, 0, stream>>>(Qb, Kb, Vt, AO);

  gemm64<1><<<(M_TOK / 64) * (DQ / 128), 256, 0, stream>>>(
      AO, wprojT, b_proj, out, nullptr, nullptr, nullptr, M_TOK, DQ, DQ, DQ / 128);
}

// Round 20
// 142.859 us; speedup vs baseline: 1.1712x; 1.0037x over previous
//
#include <hip/hip_runtime.h>

// MHA forward: B=4, S=2048, D=768, H=12, Hd=64
// prep -> qkv GEMM (64x128 tile, 3 blocks/CU, BK=64 swizzled, per-block
// operand swap) -> flash attn (R15 + packed P-cvt + 4-way l-sum tree)
// -> proj GEMM (same 64x128 structure).

typedef _Float16 f16;
typedef _Float16 f16x8 __attribute__((ext_vector_type(8)));
typedef _Float16 f16x4 __attribute__((ext_vector_type(4)));
typedef _Float16 f16x2 __attribute__((ext_vector_type(2)));
typedef __fp16 fp16v2 __attribute__((ext_vector_type(2)));   // builtin return type
typedef float f32x4 __attribute__((ext_vector_type(4)));

#define BQ 4
#define SQ 2048
#define DQ 768
#define HQ 12
#define HD 64
#define M_TOK (BQ*SQ)      // 8192
#define KVB 64
#define QSCALE 0.18033688f  // 0.125 * log2(e): scores land in exp2 domain
#define THR_LOG2 11.5f      // defer-max threshold (~e^8)

__device__ __forceinline__ void gld_lds16(const f16* g, f16* l) {
  __builtin_amdgcn_global_load_lds((const __attribute__((address_space(1))) void*)g,
                                   (__attribute__((address_space(3))) void*)l,
                                   16, 0, 0);
}

// ---- prep: cvt x (blocks 0..6143), transpose w_qkv (6144..7871), w_proj (7872..8447)
__global__ __launch_bounds__(256)
void prep(const float* __restrict__ x, f16* __restrict__ xh,
          const float* __restrict__ w_qkv, f16* __restrict__ wqkvT,
          const float* __restrict__ w_proj, f16* __restrict__ wprojT)
{
  __shared__ float tile[32][33];
  const int bid = blockIdx.x, tid = threadIdx.x;
  if (bid < 6144) {
    int i = (bid * 256 + tid) * 4;
    float4 v = *(const float4*)(x + i);
    f16x4 o = { (f16)v.x, (f16)v.y, (f16)v.z, (f16)v.w };
    *(f16x4*)(xh + i) = o;
    return;
  }
  const float* w; f16* wt; int K, N, nb, kb;
  if (bid < 7872) {
    int b2 = bid - 6144; w = w_qkv; wt = wqkvT; K = DQ; N = 3 * DQ;
    nb = (b2 % 72) * 32; kb = (b2 / 72) * 32;
  } else {
    int b3 = bid - 7872; w = w_proj; wt = wprojT; K = DQ; N = DQ;
    nb = (b3 % 24) * 32; kb = (b3 / 24) * 32;
  }
  int tx = tid & 31, ty = tid >> 5;
  for (int r = ty; r < 32; r += 8)
    tile[r][tx] = w[(size_t)(kb + r) * N + nb + tx];
  __syncthreads();
  for (int r = ty; r < 32; r += 8)
    wt[(size_t)(nb + r) * K + kb + tx] = (f16)tile[tx][r];
}

// ---- 64x128 tile GEMM, 4 waves (wave tile 32x64), BK=64 swizzled dbuf.
// LDS 48 KB -> 3 blocks/CU. MODE 0: qkv (per-block operand swap; Q/K swapped
// f16x4 scatter, V normal f16x4 into V^T). MODE 1: proj (swapped, float4).
template<int MODE>
__global__ __launch_bounds__(256, 3)
void gemm64(const f16* __restrict__ A, const f16* __restrict__ Bt,
            const float* __restrict__ bias, float* __restrict__ Cf,
            f16* __restrict__ Qb, f16* __restrict__ Kb, f16* __restrict__ Vt,
            int M, int N, int K, int nbx)
{
  __shared__ f16 Ash[2][64 * 64];    // 2 x 8 KB
  __shared__ f16 Bsh[2][128 * 64];   // 2 x 16 KB
  const int tid = threadIdx.x;
  const int cpx = gridDim.x >> 3;
  const int bid = (blockIdx.x & 7) * cpx + (blockIdx.x >> 3);
  const int nb = bid % nbx, mb = bid / nbx;
  const int m0 = mb * 64, n0 = nb * 128;
  const int lane = tid & 63, wid = tid >> 6;
  const int wr = wid >> 1, wc = wid & 1;
  const int l16 = lane & 15, l4 = lane >> 4;

  f32x4 acc[2][4] = {};

  const f16* aP[2]; int aOff[2];
  const f16* bP[4]; int bOff[4];
  #pragma unroll
  for (int j = 0; j < 2; ++j) {
    int q = j * 256 + tid;
    int r = q >> 3;
    int sc = ((q & 7) ^ (r & 7)) * 8;
    aP[j] = A + (size_t)(m0 + r) * K + sc;
    aOff[j] = q * 8;
  }
  #pragma unroll
  for (int j = 0; j < 4; ++j) {
    int q = j * 256 + tid;
    int r = q >> 3;
    int sc = ((q & 7) ^ (r & 7)) * 8;
    bP[j] = Bt + (size_t)(n0 + r) * K + sc;
    bOff[j] = q * 8;
  }

#define PSTAGE(buf, k0)                                   \
  do {                                                    \
    _Pragma("unroll")                                     \
    for (int j = 0; j < 2; ++j)                           \
      gld_lds16(aP[j] + (k0), Ash[buf] + aOff[j]);        \
    _Pragma("unroll")                                     \
    for (int j = 0; j < 4; ++j)                           \
      gld_lds16(bP[j] + (k0), Bsh[buf] + bOff[j]);        \
  } while (0)

#define KLOOP(SWAPPED)                                                        \
  for (int k0 = 0; k0 < K; k0 += 64) {                                        \
    const int buf = (k0 >> 6) & 1;                                            \
    if (k0 + 64 < K) PSTAGE(buf ^ 1, k0 + 64);                                \
    _Pragma("unroll")                                                         \
    for (int kk = 0; kk < 2; ++kk) {                                          \
      f16x8 af[2], bfr[4];                                                    \
      _Pragma("unroll")                                                       \
      for (int m = 0; m < 2; ++m) {                                           \
        int R = wr * 32 + m * 16 + l16;                                       \
        af[m] = *(const f16x8*)(Ash[buf] + R * 64 + (((kk * 4 + l4) ^ (R & 7)) * 8)); \
      }                                                                       \
      _Pragma("unroll")                                                       \
      for (int n = 0; n < 4; ++n) {                                           \
        int R = wc * 64 + n * 16 + l16;                                       \
        bfr[n] = *(const f16x8*)(Bsh[buf] + R * 64 + (((kk * 4 + l4) ^ (R & 7)) * 8)); \
      }                                                                       \
      _Pragma("unroll")                                                       \
      for (int m = 0; m < 2; ++m)                                             \
        _Pragma("unroll")                                                     \
        for (int n = 0; n < 4; ++n) {                                         \
          if (SWAPPED)                                                        \
            acc[m][n] = __builtin_amdgcn_mfma_f32_16x16x32_f16(bfr[n], af[m], acc[m][n], 0, 0, 0); \
          else                                                                \
            acc[m][n] = __builtin_amdgcn_mfma_f32_16x16x32_f16(af[m], bfr[n], acc[m][n], 0, 0, 0); \
        }                                                                     \
    }                                                                         \
    __syncthreads();                                                          \
  }

  const int cbase = n0 + wc * 64;
  const int rbase = m0 + wr * 32;
  const int which = (MODE == 1) ? 0 : (cbase / DQ);
  const bool swapped = (MODE == 1) || (which < 2);

  PSTAGE(0, 0);
  __syncthreads();
  if (swapped) { KLOOP(true) } else { KLOOP(false) }
#undef KLOOP
#undef PSTAGE

  if (MODE == 1) {
    #pragma unroll
    for (int n = 0; n < 4; ++n) {
      const int c0 = cbase + n * 16 + l4 * 4;
      const float4 bv = *(const float4*)(bias + c0);
      #pragma unroll
      for (int m = 0; m < 2; ++m) {
        const int s = rbase + m * 16 + l16;
        float4 ov = { acc[m][n][0] + bv.x, acc[m][n][1] + bv.y,
                      acc[m][n][2] + bv.z, acc[m][n][3] + bv.w };
        *(float4*)(Cf + (size_t)s * N + c0) = ov;
      }
    }
  } else if (which < 2) {
    f16* dst = which ? Kb : Qb;
    const int h = (cbase - which * DQ) >> 6;
    #pragma unroll
    for (int n = 0; n < 4; ++n) {
      const int c0 = cbase + n * 16 + l4 * 4;
      const float4 bv = *(const float4*)(bias + c0);
      const int hd0 = n * 16 + l4 * 4;
      #pragma unroll
      for (int m = 0; m < 2; ++m) {
        const int st = rbase + m * 16 + l16;
        const int b = st >> 11, s = st & 2047;
        const size_t bh = (size_t)(b * HQ + h);
        float v0 = acc[m][n][0] + bv.x, v1 = acc[m][n][1] + bv.y;
        float v2 = acc[m][n][2] + bv.z, v3 = acc[m][n][3] + bv.w;
        if (!which) { v0 *= QSCALE; v1 *= QSCALE; v2 *= QSCALE; v3 *= QSCALE; }
        f16x4 ov = { (f16)v0, (f16)v1, (f16)v2, (f16)v3 };
        *(f16x4*)(dst + (bh * SQ + s) * HD + hd0) = ov;
      }
    }
  } else {
    #pragma unroll
    for (int n = 0; n < 4; ++n) {
      int c = cbase + n * 16 + l16;
      float bv = bias[c];
      int rem = c - 2 * DQ;
      int h = rem >> 6, hd = rem & 63;
      #pragma unroll
      for (int m = 0; m < 2; ++m) {
        int rr0 = rbase + m * 16 + l4 * 4;
        int b = rr0 >> 11, s = rr0 & 2047;
        size_t bh = (size_t)(b * HQ + h);
        f16x4 ov = { (f16)(acc[m][n][0] + bv), (f16)(acc[m][n][1] + bv),
                     (f16)(acc[m][n][2] + bv), (f16)(acc[m][n][3] + bv) };
        *(f16x4*)(Vt + (bh * HD + hd) * SQ + s) = ov;
      }
    }
  }
}

// K-row permutation (C-slot -> PV B-slot mapping)
__device__ __forceinline__ int permK(int p) {
  return ((p & 16) << 1) | (((p >> 2) & 3) << 3) | ((p & 32) >> 3) | (p & 3);
}

// ---- flash attention (R15 + packed P-conversion + 4-way l-sum tree) ----
__global__ __launch_bounds__(256, 3)
void attn(const f16* __restrict__ Qb, const f16* __restrict__ Kb,
          const f16* __restrict__ Vt, f16* __restrict__ O)
{
  __shared__ f16 Ksh[2][KVB * HD];
  __shared__ f16 Vsh[2][HD * KVB];
  const int tid = threadIdx.x, lane = tid & 63, wid = tid >> 6;
  const int l16 = lane & 15, l4 = lane >> 4;

  const int nwg = gridDim.x;
  const int cpx = nwg >> 3;
  const int swz = (blockIdx.x & 7) * cpx + (blockIdx.x >> 3);
  const int qt = swz & 15, bh = swz >> 4;
  const int b = bh / HQ, h = bh - b * HQ;
  const f16* q  = Qb + (size_t)bh * SQ * HD;
  const f16* kp = Kb + (size_t)bh * SQ * HD;
  const f16* vp = Vt + (size_t)bh * HD * SQ;
  const int s0 = qt * 128 + wid * 32;

  f16x8 qf[2][2];
  #pragma unroll
  for (int g = 0; g < 2; ++g)
    #pragma unroll
    for (int kk = 0; kk < 2; ++kk)
      qf[g][kk] = *(const f16x8*)(q + (size_t)(s0 + g * 16 + l16) * HD + kk * 32 + l4 * 8);

  f32x4 oacc[2][4] = {};
  float mrun[2] = { -1e30f, -1e30f };
  float lrun[2] = { 0.f, 0.f };        // per-lane partials, row-reduced at end

  const int p0 = tid >> 3, p1 = (tid >> 3) + 32;
  const int scS = ((tid & 7) ^ (p0 & 7)) * 8;
  const int kr0 = permK(p0), kr1 = permK(p1);

#define STAGE(buf, t0)                                                        \
  do {                                                                        \
    gld_lds16(kp + (size_t)((t0) + kr0) * HD + scS, Ksh[buf] + tid * 8);      \
    gld_lds16(kp + (size_t)((t0) + kr1) * HD + scS, Ksh[buf] + (tid + 256) * 8);\
    gld_lds16(vp + (size_t)p0 * SQ + (t0) + scS,   Vsh[buf] + tid * 8);       \
    gld_lds16(vp + (size_t)p1 * SQ + (t0) + scS,   Vsh[buf] + (tid + 256) * 8);\
  } while (0)

// softmax for group g: per-lane partial max defer-check; packed f16 cvt
// (v_cvt_pkrtz) into 32-bit lanes of bfr; 4 independent l-accumulators.
#define SOFTMAX(g)                                                            \
  do {                                                                        \
    float rm = -1e30f;                                                        \
    _Pragma("unroll")                                                         \
    for (int n = 0; n < 4; ++n)                                               \
      rm = fmaxf(rm, fmaxf(fmaxf(sacc[g][n][0], sacc[g][n][1]),               \
                           fmaxf(sacc[g][n][2], sacc[g][n][3])));             \
    if (!__all(rm - mrun[g] <= THR_LOG2)) {                                   \
      rm = fmaxf(rm, __shfl_xor(rm, 16));                                     \
      rm = fmaxf(rm, __shfl_xor(rm, 32));                                     \
      float mn = fmaxf(mrun[g], rm);                                          \
      float corr = __builtin_amdgcn_exp2f(mrun[g] - mn);                      \
      lrun[g] *= corr;                                                        \
      _Pragma("unroll")                                                       \
      for (int n = 0; n < 4; ++n)                                             \
        oacc[g][n] *= corr;                                                   \
      mrun[g] = mn;                                                           \
    }                                                                         \
    float mref = mrun[g];                                                     \
    float ps0 = 0.f, ps1 = 0.f, ps2 = 0.f, ps3 = 0.f;                         \
    _Pragma("unroll")                                                         \
    for (int n = 0; n < 4; ++n) {                                             \
      float pv0 = __builtin_amdgcn_exp2f(sacc[g][n][0] - mref);               \
      float pv1 = __builtin_amdgcn_exp2f(sacc[g][n][1] - mref);               \
      float pv2 = __builtin_amdgcn_exp2f(sacc[g][n][2] - mref);               \
      float pv3 = __builtin_amdgcn_exp2f(sacc[g][n][3] - mref);               \
      ps0 += pv0; ps1 += pv1; ps2 += pv2; ps3 += pv3;                         \
      fp16v2 pa = __builtin_amdgcn_cvt_pkrtz(pv0, pv1);                       \
      fp16v2 pb = __builtin_amdgcn_cvt_pkrtz(pv2, pv3);                       \
      f16x2* bw = (f16x2*)&bfr[g][n & 1];                                     \
      bw[(n >> 1) * 2]     = *(f16x2*)&pa;                                    \
      bw[(n >> 1) * 2 + 1] = *(f16x2*)&pb;                                    \
    }                                                                         \
    lrun[g] += (ps0 + ps1) + (ps2 + ps3);                                     \
  } while (0)

#define COMPUTE(buf)                                                          \
  do {                                                                        \
    f32x4 sacc[2][4] = {};                                                    \
    f16x8 kf[2][4];                                                           \
    _Pragma("unroll")                                                         \
    for (int kk = 0; kk < 2; ++kk)                                            \
      _Pragma("unroll")                                                       \
      for (int n = 0; n < 4; ++n)                                             \
        kf[kk][n] = *(const f16x8*)(Ksh[buf] + (n * 16 + l16) * HD +          \
                                    ((kk * 32 + l4 * 8) ^ ((l16 & 7) * 8)));  \
    __builtin_amdgcn_s_setprio(1);                                            \
    _Pragma("unroll")                                                         \
    for (int kk = 0; kk < 2; ++kk)                                            \
      _Pragma("unroll")                                                       \
      for (int n = 0; n < 4; ++n)                                             \
        sacc[0][n] = __builtin_amdgcn_mfma_f32_16x16x32_f16(kf[kk][n], qf[0][kk], sacc[0][n], 0, 0, 0); \
    _Pragma("unroll")                                                         \
    for (int kk = 0; kk < 2; ++kk)                                            \
      _Pragma("unroll")                                                       \
      for (int n = 0; n < 4; ++n)                                             \
        sacc[1][n] = __builtin_amdgcn_mfma_f32_16x16x32_f16(kf[kk][n], qf[1][kk], sacc[1][n], 0, 0, 0); \
    __builtin_amdgcn_s_setprio(0);                                            \
    f16x8 vf[2][4];                                                           \
    _Pragma("unroll")                                                         \
    for (int kk = 0; kk < 2; ++kk)                                            \
      _Pragma("unroll")                                                       \
      for (int n = 0; n < 4; ++n)                                             \
        vf[kk][n] = *(const f16x8*)(Vsh[buf] + (n * 16 + l16) * KVB +         \
                                    ((kk * 32 + l4 * 8) ^ ((l16 & 7) * 8)));  \
    f16x8 bfr[2][2];                                                          \
    SOFTMAX(0);                                                               \
    __builtin_amdgcn_s_setprio(1);                                            \
    _Pragma("unroll")                                                         \
    for (int kk = 0; kk < 2; ++kk)                                            \
      _Pragma("unroll")                                                       \
      for (int n = 0; n < 4; ++n)                                             \
        oacc[0][n] = __builtin_amdgcn_mfma_f32_16x16x32_f16(vf[kk][n], bfr[0][kk], oacc[0][n], 0, 0, 0); \
    __builtin_amdgcn_s_setprio(0);                                            \
    SOFTMAX(1);                                                               \
    __builtin_amdgcn_s_setprio(1);                                            \
    _Pragma("unroll")                                                         \
    for (int kk = 0; kk < 2; ++kk)                                            \
      _Pragma("unroll")                                                       \
      for (int n = 0; n < 4; ++n)                                             \
        oacc[1][n] = __builtin_amdgcn_mfma_f32_16x16x32_f16(vf[kk][n], bfr[1][kk], oacc[1][n], 0, 0, 0); \
    __builtin_amdgcn_s_setprio(0);                                            \
  } while (0)

  STAGE(0, 0);
  __syncthreads();
  for (int t0 = 0; t0 < SQ; t0 += 2 * KVB) {
    STAGE(1, t0 + KVB);
    COMPUTE(0);
    __syncthreads();
    if (t0 + 2 * KVB < SQ) STAGE(0, t0 + 2 * KVB);
    COMPUTE(1);
    __syncthreads();
  }
#undef STAGE
#undef COMPUTE
#undef SOFTMAX

  #pragma unroll
  for (int g = 0; g < 2; ++g) {
    float lt = lrun[g];
    lt += __shfl_xor(lt, 16);
    lt += __shfl_xor(lt, 32);
    float inv = 1.f / lt;
    const int s = s0 + g * 16 + l16;
    f16* obase = O + ((size_t)b * SQ + s) * DQ + h * HD + l4 * 4;
    #pragma unroll
    for (int n = 0; n < 4; ++n) {
      f16x4 ov = { (f16)(oacc[g][n][0] * inv), (f16)(oacc[g][n][1] * inv),
                   (f16)(oacc[g][n][2] * inv), (f16)(oacc[g][n][3] * inv) };
      *(f16x4*)(obase + n * 16) = ov;
    }
  }
}

extern "C" void kernel_launch(void* const* d_in, const int* in_sizes, int n_in,
                              void* d_out, int out_size, void* d_ws, size_t ws_size,
                              hipStream_t stream) {
  const float* x      = (const float*)d_in[0];
  const float* w_qkv  = (const float*)d_in[1];
  const float* b_qkv  = (const float*)d_in[2];
  const float* w_proj = (const float*)d_in[3];
  const float* b_proj = (const float*)d_in[4];
  float* out = (float*)d_out;

  char* ws = (char*)d_ws;
  f16* xh     = (f16*)ws; ws += (size_t)M_TOK * DQ * 2;
  f16* wqkvT  = (f16*)ws; ws += (size_t)3 * DQ * DQ * 2;
  f16* wprojT = (f16*)ws; ws += (size_t)DQ * DQ * 2;
  f16* Qb     = (f16*)ws; ws += (size_t)M_TOK * DQ * 2;
  f16* Kb     = (f16*)ws; ws += (size_t)M_TOK * DQ * 2;
  f16* Vt     = (f16*)ws; ws += (size_t)M_TOK * DQ * 2;
  f16* AO     = xh;  // attn output; xh fully consumed by qkv GEMM before attn

  prep<<<8448, 256, 0, stream>>>(x, xh, w_qkv, wqkvT, w_proj, wprojT);

  gemm64<0><<<(M_TOK / 64) * (3 * DQ / 128), 256, 0, stream>>>(
      xh, wqkvT, b_qkv, nullptr, Qb, Kb, Vt, M_TOK, 3 * DQ, DQ, 3 * DQ / 128);

  attn<<<BQ * HQ * (SQ / 128), 256, 0, stream>>>(Qb, Kb, Vt, AO);

  gemm64<1><<<(M_TOK / 64) * (DQ / 128), 256, 0, stream>>>(
      AO, wprojT, b_proj, out, nullptr, nullptr, nullptr, M_TOK, DQ, DQ, DQ / 128);
}